// Round 2
// baseline (10412.536 us; speedup 1.0000x reference)
//
#include <hip/hip_runtime.h>
#include <hip/hip_bf16.h>

#define TLEN 512
#define NB   32
#define HID  768
#define NBLK 68
#define PERLINE 17   // NBLK/4 arrivals per counter line

typedef __attribute__((ext_vector_type(8))) short bf16x8;
typedef __attribute__((ext_vector_type(4))) float f32x4;
typedef unsigned short u16;
typedef unsigned int u32;
typedef unsigned long long u64;

__device__ __forceinline__ float bf2f(u16 u) {
  u32 t = ((u32)u) << 16; float f; __builtin_memcpy(&f, &t, 4); return f;
}
__device__ __forceinline__ u16 f2bf(float f) {
  u32 t; __builtin_memcpy(&t, &f, 4);
  u32 r = t + 0x7FFFu + ((t >> 16) & 1u);
  return (u16)(r >> 16);
}
// dual-dtype scalar loads: f!=0 -> input buffer is fp32, else packed bf16
__device__ __forceinline__ u16 ldbf(const void* p, size_t i, u32 f) {
  return f ? f2bf(((const float*)p)[i]) : ((const u16*)p)[i];
}
__device__ __forceinline__ float ldf(const void* p, size_t i, u32 f) {
  return f ? ((const float*)p)[i] : bf2f(((const u16*)p)[i]);
}
__device__ __forceinline__ float sigm(float x) { return 1.0f / (1.0f + __expf(-x)); }
__device__ __forceinline__ float tanh_(float x) { return 1.0f - 2.0f / (1.0f + __expf(2.0f * x)); }

// ---- agent-scope (cross-XCD coherent) accesses: bypass stale L2 ----
__device__ __forceinline__ u64 cld64(const u16* p) {
  return __hip_atomic_load((const u64*)p, __ATOMIC_RELAXED, __HIP_MEMORY_SCOPE_AGENT);
}
__device__ __forceinline__ void cst64(u16* p, u64 v) {
  __hip_atomic_store((u64*)p, v, __ATOMIC_RELAXED, __HIP_MEMORY_SCOPE_AGENT);
}
__device__ __forceinline__ bf16x8 cld128(const u16* p) {
  union { u64 q[2]; bf16x8 v; } u;
  u.q[0] = cld64(p); u.q[1] = cld64(p + 4);
  return u.v;
}
// wave-internal LDS fence (lockstep wave64: write->fence->read is safe)
__device__ __forceinline__ void wfence() {
  asm volatile("s_waitcnt lgkmcnt(0)" ::: "memory");
}

// ---------------- prologue: dtype sniff + h0/c0 conversion -------------------
__global__ __launch_bounds__(256) void prologue(const void* __restrict__ x,
                                                const void* __restrict__ h0,
                                                const void* __restrict__ c0,
                                                u32* __restrict__ flag,
                                                u16* __restrict__ h0b,
                                                float* __restrict__ c0f) {
  __shared__ u32 sflag;
  if (threadIdx.x == 0) {
    const u32* w = (const u32*)x;
    int cnt = 0;
    for (int m = 0; m < 256; ++m) {
      u32 e = ((w[m] & 0xFFFFu) >> 7) & 0xFFu;
      cnt += (e >= 100u && e <= 140u) ? 1 : 0;
    }
    sflag = (cnt >= 128) ? 0u : 1u;  // 1 = fp32 inputs
    flag[0] = sflag;
  }
  __syncthreads();
  const u32 f = sflag;
  for (int i = threadIdx.x; i < NB * HID; i += 256) {
    h0b[i] = ldbf(h0, i, f);
    c0f[i] = ldf(c0, i, f);
  }
}

// ---------------- transpose (R x C row-major -> C x R, emits bf16) ----------
__global__ __launch_bounds__(256) void transpose_any(const void* __restrict__ in,
                                                     u16* __restrict__ out, int R, int C,
                                                     const u32* __restrict__ flag) {
  const u32 f = flag[0];
  __shared__ u16 tile[64][65];
  int c0 = blockIdx.x * 64, r0 = blockIdx.y * 64;
  int tx = threadIdx.x & 63, ty = threadIdx.x >> 6;
#pragma unroll
  for (int j = 0; j < 16; ++j) {
    int r = ty + 4 * j;
    tile[r][tx] = ldbf(in, (size_t)(r0 + r) * C + c0 + tx, f);
  }
  __syncthreads();
#pragma unroll
  for (int j = 0; j < 16; ++j) {
    int r = ty + 4 * j;
    out[(size_t)(c0 + r) * R + r0 + tx] = tile[tx][r];
  }
}

// ---------------- QKV precompute: [16384 x 768] @ [768 x 2304] --------------
__global__ __launch_bounds__(256) void qkv_gemm(const void* __restrict__ X, const u16* __restrict__ WT,
                                                const void* __restrict__ bq, const void* __restrict__ bk,
                                                const void* __restrict__ bv,
                                                u16* __restrict__ Qx, u16* __restrict__ Kx,
                                                u16* __restrict__ Vx, const u32* __restrict__ flag) {
  const u32 f = flag[0];
  __shared__ __align__(16) u16 As[128][40];
  __shared__ __align__(16) u16 Bs[128][40];
  const int m0 = blockIdx.x * 128;
  const int n0 = blockIdx.y * 128;
  const int tid = threadIdx.x;
  const int lane = tid & 63, w = tid >> 6;
  const int l15 = lane & 15, l4 = lane >> 4;
  f32x4 zero4 = {0.f, 0.f, 0.f, 0.f};
  f32x4 acc[2][8];
#pragma unroll
  for (int h = 0; h < 2; ++h)
#pragma unroll
    for (int nt = 0; nt < 8; ++nt) acc[h][nt] = zero4;
  const int srow = tid >> 1, skp = (tid & 1) * 16;
  for (int k0 = 0; k0 < 768; k0 += 32) {
    __syncthreads();
    if (f) {
      const float* Xf = (const float*)X + (size_t)(m0 + srow) * 768 + k0 + skp;
#pragma unroll
      for (int q = 0; q < 16; ++q) As[srow][skp + q] = f2bf(Xf[q]);
    } else {
      const u16* Xh = (const u16*)X + (size_t)(m0 + srow) * 768 + k0 + skp;
      *(bf16x8*)&As[srow][skp]     = *(const bf16x8*)(Xh);
      *(bf16x8*)&As[srow][skp + 8] = *(const bf16x8*)(Xh + 8);
    }
    *(bf16x8*)&Bs[srow][skp]     = *(const bf16x8*)(WT + (size_t)(n0 + srow) * 768 + k0 + skp);
    *(bf16x8*)&Bs[srow][skp + 8] = *(const bf16x8*)(WT + (size_t)(n0 + srow) * 768 + k0 + skp + 8);
    __syncthreads();
    const int kl = 8 * l4;
    bf16x8 a0 = *(const bf16x8*)&As[32 * w + l15][kl];
    bf16x8 a1 = *(const bf16x8*)&As[32 * w + 16 + l15][kl];
#pragma unroll
    for (int nt = 0; nt < 8; ++nt) {
      bf16x8 b = *(const bf16x8*)&Bs[16 * nt + l15][kl];
      acc[0][nt] = __builtin_amdgcn_mfma_f32_16x16x32_bf16(a0, b, acc[0][nt], 0, 0, 0);
      acc[1][nt] = __builtin_amdgcn_mfma_f32_16x16x32_bf16(a1, b, acc[1][nt], 0, 0, 0);
    }
  }
#pragma unroll
  for (int h = 0; h < 2; ++h)
#pragma unroll
    for (int nt = 0; nt < 8; ++nt)
#pragma unroll
      for (int r = 0; r < 4; ++r) {
        const int m = m0 + 32 * w + 16 * h + 4 * l4 + r;
        const int n = n0 + 16 * nt + l15;
        float bias; u16* dst;
        if (n < 768)       { bias = ldf(bq, n, f);        dst = Qx + (size_t)m * 768 + n; }
        else if (n < 1536) { bias = ldf(bk, n - 768, f);  dst = Kx + (size_t)m * 768 + (n - 768); }
        else               { bias = ldf(bv, n - 1536, f); dst = Vx + (size_t)m * 768 + (n - 1536); }
        *dst = f2bf(acc[h][nt][r] + bias);
      }
}

// ---------------- persistent sequential scan ---------------------------------
// 68 blocks x 384 threads (6 waves). bid<48: gates (4 compute waves K-split-4
// over the block's 64 gate-cols, 2 stager waves stage the 96KB A=[row|h] tile);
// bid<60: kv (4 compute waves as before, 2 stagers stage the 48KB row tile);
// bid<68: attn (4 batch waves, 2 idle). K-split partials are reduced via an
// LDS f32 buffer laid out [w][b][4m+q] so one ds_read_b128 yields (i,f,g,o).
struct ScanParams {
  const void *x, *bih, *bhh, *bk, *bv;
  const u16 *h0b;
  const float *c0f;
  const int* ping;
  const u16 *WihT, *WhhT, *WqkvT;
  const u16 *Qx;
  u16 *Kx, *Vx;
  u16 *rowbuf, *hsb;
  void* out;
  u32 *ctr;       // [0,32,64,96]=arrival lines, [320]=kvctr
  const u32* flag;
};

// drain all waves' stores, then one arrival per block
__device__ __forceinline__ void g_sync_arrive(u32* ctr, int bid) {
  __builtin_amdgcn_s_waitcnt(0);
  __syncthreads();
  if (threadIdx.x == 0)
    __hip_atomic_fetch_add(&ctr[(bid & 3) * 32], 1u, __ATOMIC_RELAXED, __HIP_MEMORY_SCOPE_AGENT);
}
// wave 0 polls the 4 lines directly; broadcasts to other waves via LDS flag
__device__ __forceinline__ void g_wait(u32* ctr, u32 z, u32* sep) {
  if (threadIdx.x < 64) {
    const u32 tgt = PERLINE * z;
    for (;;) {
      u32 mine = tgt;
      if (threadIdx.x < 4)
        mine = __hip_atomic_load(&ctr[threadIdx.x * 32], __ATOMIC_RELAXED, __HIP_MEMORY_SCOPE_AGENT);
      if (__all(mine >= tgt)) break;
      __builtin_amdgcn_s_sleep(1);
    }
    if (threadIdx.x == 0)
      __hip_atomic_store(sep, z, __ATOMIC_RELAXED, __HIP_MEMORY_SCOPE_WORKGROUP);
  } else {
    while (__hip_atomic_load(sep, __ATOMIC_RELAXED, __HIP_MEMORY_SCOPE_WORKGROUP) < z)
      __builtin_amdgcn_s_sleep(1);
  }
  asm volatile("" ::: "memory");
}

__global__ __launch_bounds__(384, 2) void scan_kernel(ScanParams P) {
  // LDS layout (union across roles):
  //  gates: As 0..98304 | P 98304..133120 ([4][32][68] f32) | htile 133120..134144
  //         | biasT 134144..134400
  //  kv:    As 0..49152 | tile 49152..57344 (per-wave [32][32] u16)
  //  attn:  sbuf 0..18432 | sping 18432..26624
  //  all:   sep @134400
  __shared__ __align__(16) unsigned char SH[134448];
  const int bid = blockIdx.x;
  const int tid = threadIdx.x;
  const int wid = tid >> 6;
  const int lane = tid & 63;
  const int l15 = lane & 15, l4 = lane >> 4;
  const u32 f = P.flag[0];
  u32* ctr = P.ctr;
  u32* sep = (u32*)(SH + 134400);
  if (tid == 0) *sep = 0;
  u32 z = 1;

  if (bid < 48) {
    u16* As = (u16*)SH;                       // [32 rows][192 chunks][8], XOR-swizzled
    float* Pp = (float*)(SH + 98304);         // [4][32][68] partial gate sums
    u16* htile = (u16*)(SH + 133120);         // [32][16]
    float* biasT = (float*)(SH + 134144);     // [64] = bias[4m+q]
    const int jb = 16 * bid;                  // block's 16 hidden cols

    if (wid < 4) {
      // ---- compute wave w: all 64 gate-cols, K-range [384w, 384w+384) -------
      const int w = wid;
      const int cq = l15 & 3, cm4 = l15 >> 2;   // col n=16nt+l15 <-> (q=cq, m=4nt+cm4)
      bf16x8 Bfr[12][4];
      {
        const u16* WT = (w < 2) ? P.WihT : P.WhhT;
        const int kbase = 384 * (w & 1);
#pragma unroll
        for (int s = 0; s < 12; ++s)
#pragma unroll
          for (int nt = 0; nt < 4; ++nt) {
            const int colW = 768 * cq + jb + 4 * nt + cm4;
            Bfr[s][nt] = *(const bf16x8*)(WT + (size_t)colW * HID + kbase + 32 * s + 8 * l4);
          }
      }
      if (w == 0) {  // bias table: biasT[4m+q]
        const int m_ = lane >> 2, q_ = lane & 3;
        biasT[lane] = ldf(P.bih, 768 * q_ + jb + m_, f) + ldf(P.bhh, 768 * q_ + jb + m_, f);
      }
      const int cb = 8 * w + (lane >> 3), cm = lane & 7;  // this lane's cells (cb,cm),(cb,cm+8)
      float cst0 = P.c0f[(size_t)cb * HID + jb + cm];
      float cst1 = P.c0f[(size_t)cb * HID + jb + cm + 8];
      g_sync_arrive(ctr, bid); g_wait(ctr, z, sep); ++z;   // prologue: row_0 ready

      for (int i = 0; i < TLEN; ++i) {
        __syncthreads();   // sync1: As staged
        f32x4 zero4 = {0.f, 0.f, 0.f, 0.f};
        f32x4 acc[2][4];
#pragma unroll
        for (int h = 0; h < 2; ++h)
#pragma unroll
          for (int nt = 0; nt < 4; ++nt) acc[h][nt] = zero4;
        const int cbase = 48 * w;
#pragma unroll
        for (int s = 0; s < 12; ++s) {
          const int cc = (cbase + 4 * s + l4) ^ (l15 & 7);
          bf16x8 a0 = *(const bf16x8*)&As[((size_t)l15 * 192 + cc) * 8];
          bf16x8 a1 = *(const bf16x8*)&As[((size_t)(l15 + 16) * 192 + cc) * 8];
#pragma unroll
          for (int nt = 0; nt < 4; ++nt) {
            acc[0][nt] = __builtin_amdgcn_mfma_f32_16x16x32_bf16(a0, Bfr[s][nt], acc[0][nt], 0, 0, 0);
            acc[1][nt] = __builtin_amdgcn_mfma_f32_16x16x32_bf16(a1, Bfr[s][nt], acc[1][nt], 0, 0, 0);
          }
        }
        // partials -> LDS [w][row][16nt + 4cm4 + cq]
        float* Pw = Pp + 2176 * w;
#pragma unroll
        for (int h = 0; h < 2; ++h)
#pragma unroll
          for (int nt = 0; nt < 4; ++nt)
#pragma unroll
            for (int r = 0; r < 4; ++r)
              Pw[(16 * h + 4 * l4 + r) * 68 + 16 * nt + 4 * cm4 + cq] = acc[h][nt][r];
        __syncthreads();   // sync2
        // reduce 4 partials + bias; pointwise for cells (cb,cm),(cb,cm+8)
        f32x4 g0 = *(const f32x4*)&biasT[4 * cm];
        f32x4 g1 = *(const f32x4*)&biasT[4 * (cm + 8)];
#pragma unroll
        for (int w2 = 0; w2 < 4; ++w2) {
          g0 += *(const f32x4*)&Pp[2176 * w2 + 68 * cb + 4 * cm];
          g1 += *(const f32x4*)&Pp[2176 * w2 + 68 * cb + 4 * (cm + 8)];
        }
        cst0 = sigm(g0[1]) * cst0 + sigm(g0[0]) * tanh_(g0[2]);
        cst1 = sigm(g1[1]) * cst1 + sigm(g1[0]) * tanh_(g1[2]);
        float h0v = sigm(g0[3]) * tanh_(cst0);
        float h1v = sigm(g1[3]) * tanh_(cst1);
        htile[cb * 16 + cm] = f2bf(h0v);
        htile[cb * 16 + cm + 8] = f2bf(h1v);
        __syncthreads();   // sync3 (flusher wave writes hsb)
        g_sync_arrive(ctr, bid);
        // out stores off the critical path (drained by next step's arrive)
        const size_t o1 = (size_t)i * NB * HID + (size_t)cb * HID + jb + cm;
        if (f) { float* O = (float*)P.out; O[o1] = h0v; O[o1 + 8] = h1v; }
        else   { u16*   O = (u16*)P.out;   O[o1] = f2bf(h0v); O[o1 + 8] = f2bf(h1v); }
        if (i == TLEN - 1) {
          const size_t oh = (size_t)TLEN * NB * HID + (size_t)cb * HID + jb + cm;
          const size_t oc = (size_t)(TLEN + 1) * NB * HID + (size_t)cb * HID + jb + cm;
          if (f) { float* O = (float*)P.out; O[oh] = h0v; O[oh + 8] = h1v; O[oc] = cst0; O[oc + 8] = cst1; }
          else   { u16*   O = (u16*)P.out;   O[oh] = f2bf(h0v); O[oh + 8] = f2bf(h1v);
                   O[oc] = f2bf(cst0); O[oc + 8] = f2bf(cst1); }
        }
        g_wait(ctr, z, sep); ++z;
      }
    } else {
      // ---- stager waves (wid 4,5): stage A=[row|h] 32x1536 bf16 into LDS ----
      const int stq = (wid - 4) * 64 + lane;   // 0..127
      g_sync_arrive(ctr, bid); g_wait(ctr, z, sep); ++z;   // prologue

      for (int i = 0; i < TLEN; ++i) {
        const u16* rowp = P.rowbuf + (size_t)(i & 1) * NB * HID;
        const u16* hp = (i == 0) ? P.h0b : (P.hsb + (size_t)((i - 1) & 1) * NB * HID);
        bf16x8 stg[48];
#pragma unroll
        for (int j = 0; j < 48; ++j) {
          const int g = stq + 128 * j;
          const int r = g / 192, c = g - r * 192;
          const u16* src = (c < 96) ? (rowp + (size_t)r * HID + c * 8)
                                    : (hp + (size_t)r * HID + (c - 96) * 8);
          stg[j] = cld128(src);
        }
#pragma unroll
        for (int j = 0; j < 48; ++j) {
          const int g = stq + 128 * j;
          const int r = g / 192, c = g - r * 192;
          *(bf16x8*)&As[((size_t)r * 192 + (c ^ (r & 7))) * 8] = stg[j];
        }
        __syncthreads();   // sync1
        __syncthreads();   // sync2
        __syncthreads();   // sync3: htile complete
        if (wid == 4) {    // flush h tile -> hsb (global, coherent)
#pragma unroll
          for (int k = 0; k < 2; ++k) {
            const int idx = lane + 64 * k;
            const int b = idx >> 2, part = idx & 3;
            u64 hv; __builtin_memcpy(&hv, &htile[b * 16 + 4 * part], 8);
            cst64(P.hsb + (size_t)(i & 1) * NB * HID + (size_t)b * HID + jb + 4 * part, hv);
          }
        }
        g_sync_arrive(ctr, bid);
        g_wait(ctr, z, sep); ++z;
      }
    }
  } else if (bid < 60) {
    // ------- k/v projection: 4 compute waves (32 cols each), 2 stagers --------
    u16* As = (u16*)SH;                                  // [32][96 chunks][8]
    u16* tile = (u16*)(SH + 49152) + wid * 1024;         // [32][32] per compute wave
    if (wid < 4) {
      const int kw = (bid - 48) * 4 + wid;
      const int col0 = 32 * kw;
      const bool isV = (col0 >= 768);
      const u16* Wt = P.WqkvT + (size_t)(768 + col0) * HID;
      const int oc0 = isV ? (col0 - 768) : col0;
      u16* obase = isV ? P.Vx : P.Kx;
      const void* bias_src = isV ? P.bv : P.bk;
      const float bias0 = ldf(bias_src, oc0 + l15, f);
      const float bias1 = ldf(bias_src, oc0 + 16 + l15, f);
      bf16x8 Bfr[48];
#pragma unroll
      for (int s = 0; s < 24; ++s) {
        int k = 32 * s + 8 * l4;
        Bfr[2 * s]     = *(const bf16x8*)(Wt + (size_t)l15 * HID + k);
        Bfr[2 * s + 1] = *(const bf16x8*)(Wt + (size_t)(16 + l15) * HID + k);
      }
      g_sync_arrive(ctr, bid); g_wait(ctr, z, sep); ++z;   // prologue

      for (int i = 0; i < TLEN; ++i) {
        __syncthreads();   // As staged
        f32x4 a00 = {0.f,0.f,0.f,0.f}, a01 = {0.f,0.f,0.f,0.f};
        f32x4 a10 = {0.f,0.f,0.f,0.f}, a11 = {0.f,0.f,0.f,0.f};
#pragma unroll
        for (int s = 0; s < 24; ++s) {
          const int cc = (4 * s + l4) ^ (l15 & 7);
          bf16x8 r0 = *(const bf16x8*)&As[((size_t)l15 * 96 + cc) * 8];
          bf16x8 r1 = *(const bf16x8*)&As[((size_t)(l15 + 16) * 96 + cc) * 8];
          a00 = __builtin_amdgcn_mfma_f32_16x16x32_bf16(r0, Bfr[2 * s],     a00, 0, 0, 0);
          a01 = __builtin_amdgcn_mfma_f32_16x16x32_bf16(r0, Bfr[2 * s + 1], a01, 0, 0, 0);
          a10 = __builtin_amdgcn_mfma_f32_16x16x32_bf16(r1, Bfr[2 * s],     a10, 0, 0, 0);
          a11 = __builtin_amdgcn_mfma_f32_16x16x32_bf16(r1, Bfr[2 * s + 1], a11, 0, 0, 0);
        }
#pragma unroll
        for (int r = 0; r < 4; ++r) {
          int b0 = 4 * l4 + r;
          tile[b0 * 32 + l15]             = f2bf(a00[r] + bias0);
          tile[b0 * 32 + 16 + l15]        = f2bf(a01[r] + bias1);
          tile[(16 + b0) * 32 + l15]      = f2bf(a10[r] + bias0);
          tile[(16 + b0) * 32 + 16 + l15] = f2bf(a11[r] + bias1);
        }
        wfence();
        {
          u16* ob = obase + (size_t)i * NB * HID + oc0;
          const int row = lane >> 1, ch = (lane & 1) * 16;
#pragma unroll
          for (int q = 0; q < 4; ++q) {
            u64 w8; __builtin_memcpy(&w8, &tile[row * 32 + ch + 4 * q], 8);
            cst64(ob + (size_t)row * HID + ch + 4 * q, w8);
          }
        }
        // drain, publish kv-row-complete, arrive
        __builtin_amdgcn_s_waitcnt(0);
        __syncthreads();
        if (tid == 0) {
          __hip_atomic_fetch_add(&ctr[320], 1u, __ATOMIC_RELAXED, __HIP_MEMORY_SCOPE_AGENT);
          __hip_atomic_fetch_add(&ctr[(bid & 3) * 32], 1u, __ATOMIC_RELAXED, __HIP_MEMORY_SCOPE_AGENT);
        }
        g_wait(ctr, z, sep); ++z;
      }
    } else {
      // ---- stager waves: stage row (32 x 768 bf16) into LDS -----------------
      const int stq = (wid - 4) * 64 + lane;   // 0..127
      g_sync_arrive(ctr, bid); g_wait(ctr, z, sep); ++z;   // prologue

      for (int i = 0; i < TLEN; ++i) {
        const u16* rowp = P.rowbuf + (size_t)(i & 1) * NB * HID;
        bf16x8 stg[24];
#pragma unroll
        for (int j = 0; j < 24; ++j) {
          const int g = stq + 128 * j;
          const int r = g / 96, c = g - r * 96;
          stg[j] = cld128(rowp + (size_t)r * HID + c * 8);
        }
#pragma unroll
        for (int j = 0; j < 24; ++j) {
          const int g = stq + 128 * j;
          const int r = g / 96, c = g - r * 96;
          *(bf16x8*)&As[((size_t)r * 96 + (c ^ (r & 7))) * 8] = stg[j];
        }
        __syncthreads();   // As staged
        __builtin_amdgcn_s_waitcnt(0);
        __syncthreads();
        g_wait(ctr, z, sep); ++z;
      }
    }
  } else {
    // ------- attention: waves 0-3 = one batch each; waves 4,5 idle ------------
    const int b = (bid - 60) * 4 + wid;
    u16* sb = (u16*)SH + wid * 2304;                     // [3][768]
    int* spng = (int*)(SH + 18432) + wid * 512;
    if (wid < 4) {
      for (int j = lane; j < TLEN; j += 64) spng[j] = P.ping[(size_t)b * TLEN + j];
      {  // prologue: row_0 = x[0] (t=0 mask false)
        const size_t xoff = (size_t)b * HID + 12 * lane;
        u16* orow = P.rowbuf + (size_t)b * HID + 12 * lane;
#pragma unroll
        for (int q = 0; q < 3; ++q) {
          u16 e[4];
#pragma unroll
          for (int t2 = 0; t2 < 4; ++t2) e[t2] = ldbf(P.x, xoff + 4 * q + t2, f);
          u64 w8; __builtin_memcpy(&w8, e, 8);
          cst64(orow + 4 * q, w8);
        }
      }
    }
    g_sync_arrive(ctr, bid); g_wait(ctr, z, sep); ++z;   // prologue

    for (int i = 0; i < TLEN; ++i) {
      if (wid < 4 && i < TLEN - 1) {
        const int t = i + 1;
        const int p = spng[t];
        u16* orow = P.rowbuf + (size_t)(t & 1) * NB * HID + (size_t)b * HID;
        if (p == 0) {  // mask false -> row = x[t]
          const size_t xoff = ((size_t)t * NB + b) * HID + 12 * lane;
#pragma unroll
          for (int q = 0; q < 3; ++q) {
            u16 e[4];
#pragma unroll
            for (int t2 = 0; t2 < 4; ++t2) e[t2] = ldbf(P.x, xoff + 4 * q + t2, f);
            u64 w8; __builtin_memcpy(&w8, e, 8);
            cst64(orow + 12 * lane + 4 * q, w8);
          }
        } else {
          const int idx = p - 1;
          // q / right-key / right-value: static rows, plain loads, issued early
          const u16* qp = P.Qx + ((size_t)t * NB + b) * HID;  // never rewritten
          const u16* kR = P.Kx + ((size_t)t * NB + b) * HID;  // untouched until interval t
          const u16* vR = P.Vx + ((size_t)t * NB + b) * HID;
          float qv[12], krv[12], vrv[12];
#pragma unroll
          for (int j = 0; j < 12; ++j) {
            qv[j]  = bf2f(qp[64 * j + lane]);
            krv[j] = bf2f(kR[64 * j + lane]);
            vrv[j] = bf2f(vR[64 * j + lane]);
          }
          if (idx == i) {  // produced this interval: wait for the 12 kv blocks
            while (__hip_atomic_load(&ctr[320], __ATOMIC_RELAXED, __HIP_MEMORY_SCOPE_AGENT) <
                   12u * (u32)(i + 1)) {
              __builtin_amdgcn_s_sleep(2);
            }
            asm volatile("" ::: "memory");
          }
          const u16* kL = P.Kx + ((size_t)idx * NB + b) * HID;
          const u16* vL = P.Vx + ((size_t)idx * NB + b) * HID;
#pragma unroll
          for (int q = 0; q < 3; ++q) {
            *(u64*)&sb[12 * lane + 4 * q]       = cld64(kL + 12 * lane + 4 * q);
            *(u64*)&sb[768 + 12 * lane + 4 * q] = cld64(vL + 12 * lane + 4 * q);
          }
          wfence();
          float d0[12], d1[12];
#pragma unroll
          for (int j = 0; j < 12; ++j) {
            d0[j] = qv[j] * bf2f(sb[64 * j + lane]);
            d1[j] = qv[j] * krv[j];
          }
#pragma unroll
          for (int m = 32; m > 0; m >>= 1) {
#pragma unroll
            for (int j = 0; j < 12; ++j) {
              d0[j] += __shfl_xor(d0[j], m);
              d1[j] += __shfl_xor(d1[j], m);
            }
          }
#pragma unroll
          for (int j = 0; j < 12; ++j) {
            float pw0 = sigm((d0[j] - d1[j]) * 0.125f);  // softmax over 2 keys
            float ov = pw0 * bf2f(sb[768 + 64 * j + lane]) + (1.0f - pw0) * vrv[j];
            sb[1536 + 64 * j + lane] = f2bf(ov);
          }
          wfence();
#pragma unroll
          for (int q = 0; q < 3; ++q) {
            u64 w8; __builtin_memcpy(&w8, &sb[1536 + 12 * lane + 4 * q], 8);
            cst64(orow + 12 * lane + 4 * q, w8);
          }
        }
      }
      g_sync_arrive(ctr, bid); g_wait(ctr, z, sep); ++z;
    }
  }
}

extern "C" void kernel_launch(void* const* d_in, const int* in_sizes, int n_in,
                              void* d_out, int out_size, void* d_ws, size_t ws_size,
                              hipStream_t stream) {
  const void* x   = d_in[0];
  const int* ping = (const int*)d_in[1];
  const void* h0  = d_in[2];
  const void* c0  = d_in[3];
  const void* wih = d_in[4];
  const void* whh = d_in[5];
  const void* bih = d_in[6];
  const void* bhh = d_in[7];
  const void* wq  = d_in[8];
  const void* bq  = d_in[9];
  const void* wk  = d_in[10];
  const void* bk  = d_in[11];
  const void* wv  = d_in[12];
  const void* bv  = d_in[13];
  (void)in_sizes; (void)n_in; (void)out_size; (void)ws_size;  // needs ~90 MB ws

  char* ws = (char*)d_ws;
  size_t off = 0;
  auto walloc = [&](size_t b) { char* p = ws + off; off += (b + 255) & ~(size_t)255; return p; };
  u32* ctr    = (u32*)walloc(2048);
  u32* flag   = ctr + 400;  // clear of lines 0..96, kvctr 320
  u16* WqkvT  = (u16*)walloc((size_t)2304 * 768 * 2);
  u16* WihT   = (u16*)walloc((size_t)3072 * 768 * 2);
  u16* WhhT   = (u16*)walloc((size_t)3072 * 768 * 2);
  u16* Qx     = (u16*)walloc((size_t)TLEN * NB * HID * 2);
  u16* Kx     = (u16*)walloc((size_t)TLEN * NB * HID * 2);
  u16* Vx     = (u16*)walloc((size_t)TLEN * NB * HID * 2);
  u16* rowbuf = (u16*)walloc((size_t)2 * NB * HID * 2);
  u16* h0b    = (u16*)walloc((size_t)NB * HID * 2);
  float* c0f  = (float*)walloc((size_t)NB * HID * 4);
  u16* hsb    = (u16*)walloc((size_t)2 * NB * HID * 2);

  hipMemsetAsync(ctr, 0, 2048, stream);
  prologue<<<1, 256, 0, stream>>>(x, h0, c0, flag, h0b, c0f);
  transpose_any<<<dim3(12, 12), 256, 0, stream>>>(wq, WqkvT, 768, 768, flag);
  transpose_any<<<dim3(12, 12), 256, 0, stream>>>(wk, WqkvT + (size_t)768 * 768, 768, 768, flag);
  transpose_any<<<dim3(12, 12), 256, 0, stream>>>(wv, WqkvT + (size_t)1536 * 768, 768, 768, flag);
  transpose_any<<<dim3(48, 12), 256, 0, stream>>>(wih, WihT, 768, 3072, flag);
  transpose_any<<<dim3(48, 12), 256, 0, stream>>>(whh, WhhT, 768, 3072, flag);
  qkv_gemm<<<dim3(128, 18), 256, 0, stream>>>(x, WqkvT, bq, bk, bv, Qx, Kx, Vx, flag);

  ScanParams P;
  P.x = x; P.bih = bih; P.bhh = bhh; P.bk = bk; P.bv = bv;
  P.h0b = h0b; P.c0f = c0f;
  P.ping = ping;
  P.WihT = WihT; P.WhhT = WhhT; P.WqkvT = WqkvT;
  P.Qx = Qx; P.Kx = Kx; P.Vx = Vx;
  P.rowbuf = rowbuf; P.hsb = hsb;
  P.out = d_out;
  P.ctr = ctr; P.flag = flag;
  scan_kernel<<<dim3(NBLK), dim3(384), 0, stream>>>(P);
}

// Round 3
// 10350.018 us; speedup vs baseline: 1.0060x; 1.0060x over previous
//
#include <hip/hip_runtime.h>
#include <hip/hip_bf16.h>

#define TLEN 512
#define NB   32
#define HID  768
#define NBLK 68
#define PERLINE 17   // NBLK/4 arrivals per counter line

typedef __attribute__((ext_vector_type(8))) short bf16x8;
typedef __attribute__((ext_vector_type(4))) float f32x4;
typedef unsigned short u16;
typedef unsigned int u32;
typedef unsigned long long u64;

__device__ __forceinline__ float bf2f(u16 u) {
  u32 t = ((u32)u) << 16; float f; __builtin_memcpy(&f, &t, 4); return f;
}
__device__ __forceinline__ u16 f2bf(float f) {
  u32 t; __builtin_memcpy(&t, &f, 4);
  u32 r = t + 0x7FFFu + ((t >> 16) & 1u);
  return (u16)(r >> 16);
}
// dual-dtype scalar loads: f!=0 -> input buffer is fp32, else packed bf16
__device__ __forceinline__ u16 ldbf(const void* p, size_t i, u32 f) {
  return f ? f2bf(((const float*)p)[i]) : ((const u16*)p)[i];
}
__device__ __forceinline__ float ldf(const void* p, size_t i, u32 f) {
  return f ? ((const float*)p)[i] : bf2f(((const u16*)p)[i]);
}
__device__ __forceinline__ float sigm(float x) { return 1.0f / (1.0f + __expf(-x)); }
__device__ __forceinline__ float tanh_(float x) { return 1.0f - 2.0f / (1.0f + __expf(2.0f * x)); }

// ---- agent-scope (cross-XCD coherent) accesses: bypass stale L2 ----
__device__ __forceinline__ u64 cld64(const u16* p) {
  return __hip_atomic_load((const u64*)p, __ATOMIC_RELAXED, __HIP_MEMORY_SCOPE_AGENT);
}
__device__ __forceinline__ void cst64(u16* p, u64 v) {
  __hip_atomic_store((u64*)p, v, __ATOMIC_RELAXED, __HIP_MEMORY_SCOPE_AGENT);
}
__device__ __forceinline__ bf16x8 cld128(const u16* p) {
  union { u64 q[2]; bf16x8 v; } u;
  u.q[0] = cld64(p); u.q[1] = cld64(p + 4);
  return u.v;
}
// wave-internal LDS fence (lockstep wave64: write->fence->read is safe)
__device__ __forceinline__ void wfence() {
  asm volatile("s_waitcnt lgkmcnt(0)" ::: "memory");
}

// ---------------- prologue: dtype sniff + h0/c0 conversion -------------------
__global__ __launch_bounds__(256) void prologue(const void* __restrict__ x,
                                                const void* __restrict__ h0,
                                                const void* __restrict__ c0,
                                                u32* __restrict__ flag,
                                                u16* __restrict__ h0b,
                                                float* __restrict__ c0f) {
  __shared__ u32 sflag;
  if (threadIdx.x == 0) {
    const u32* w = (const u32*)x;
    int cnt = 0;
    for (int m = 0; m < 256; ++m) {
      u32 e = ((w[m] & 0xFFFFu) >> 7) & 0xFFu;
      cnt += (e >= 100u && e <= 140u) ? 1 : 0;
    }
    sflag = (cnt >= 128) ? 0u : 1u;  // 1 = fp32 inputs
    flag[0] = sflag;
  }
  __syncthreads();
  const u32 f = sflag;
  for (int i = threadIdx.x; i < NB * HID; i += 256) {
    h0b[i] = ldbf(h0, i, f);
    c0f[i] = ldf(c0, i, f);
  }
}

// ---------------- transpose (R x C row-major -> C x R, emits bf16) ----------
__global__ __launch_bounds__(256) void transpose_any(const void* __restrict__ in,
                                                     u16* __restrict__ out, int R, int C,
                                                     const u32* __restrict__ flag) {
  const u32 f = flag[0];
  __shared__ u16 tile[64][65];
  int c0 = blockIdx.x * 64, r0 = blockIdx.y * 64;
  int tx = threadIdx.x & 63, ty = threadIdx.x >> 6;
#pragma unroll
  for (int j = 0; j < 16; ++j) {
    int r = ty + 4 * j;
    tile[r][tx] = ldbf(in, (size_t)(r0 + r) * C + c0 + tx, f);
  }
  __syncthreads();
#pragma unroll
  for (int j = 0; j < 16; ++j) {
    int r = ty + 4 * j;
    out[(size_t)(c0 + r) * R + r0 + tx] = tile[tx][r];
  }
}

// ---------------- QKV precompute: [16384 x 768] @ [768 x 2304] --------------
__global__ __launch_bounds__(256) void qkv_gemm(const void* __restrict__ X, const u16* __restrict__ WT,
                                                const void* __restrict__ bq, const void* __restrict__ bk,
                                                const void* __restrict__ bv,
                                                u16* __restrict__ Qx, u16* __restrict__ Kx,
                                                u16* __restrict__ Vx, const u32* __restrict__ flag) {
  const u32 f = flag[0];
  __shared__ __align__(16) u16 As[128][40];
  __shared__ __align__(16) u16 Bs[128][40];
  const int m0 = blockIdx.x * 128;
  const int n0 = blockIdx.y * 128;
  const int tid = threadIdx.x;
  const int lane = tid & 63, w = tid >> 6;
  const int l15 = lane & 15, l4 = lane >> 4;
  f32x4 zero4 = {0.f, 0.f, 0.f, 0.f};
  f32x4 acc[2][8];
#pragma unroll
  for (int h = 0; h < 2; ++h)
#pragma unroll
    for (int nt = 0; nt < 8; ++nt) acc[h][nt] = zero4;
  const int srow = tid >> 1, skp = (tid & 1) * 16;
  for (int k0 = 0; k0 < 768; k0 += 32) {
    __syncthreads();
    if (f) {
      const float* Xf = (const float*)X + (size_t)(m0 + srow) * 768 + k0 + skp;
#pragma unroll
      for (int q = 0; q < 16; ++q) As[srow][skp + q] = f2bf(Xf[q]);
    } else {
      const u16* Xh = (const u16*)X + (size_t)(m0 + srow) * 768 + k0 + skp;
      *(bf16x8*)&As[srow][skp]     = *(const bf16x8*)(Xh);
      *(bf16x8*)&As[srow][skp + 8] = *(const bf16x8*)(Xh + 8);
    }
    *(bf16x8*)&Bs[srow][skp]     = *(const bf16x8*)(WT + (size_t)(n0 + srow) * 768 + k0 + skp);
    *(bf16x8*)&Bs[srow][skp + 8] = *(const bf16x8*)(WT + (size_t)(n0 + srow) * 768 + k0 + skp + 8);
    __syncthreads();
    const int kl = 8 * l4;
    bf16x8 a0 = *(const bf16x8*)&As[32 * w + l15][kl];
    bf16x8 a1 = *(const bf16x8*)&As[32 * w + 16 + l15][kl];
#pragma unroll
    for (int nt = 0; nt < 8; ++nt) {
      bf16x8 b = *(const bf16x8*)&Bs[16 * nt + l15][kl];
      acc[0][nt] = __builtin_amdgcn_mfma_f32_16x16x32_bf16(a0, b, acc[0][nt], 0, 0, 0);
      acc[1][nt] = __builtin_amdgcn_mfma_f32_16x16x32_bf16(a1, b, acc[1][nt], 0, 0, 0);
    }
  }
#pragma unroll
  for (int h = 0; h < 2; ++h)
#pragma unroll
    for (int nt = 0; nt < 8; ++nt)
#pragma unroll
      for (int r = 0; r < 4; ++r) {
        const int m = m0 + 32 * w + 16 * h + 4 * l4 + r;
        const int n = n0 + 16 * nt + l15;
        float bias; u16* dst;
        if (n < 768)       { bias = ldf(bq, n, f);        dst = Qx + (size_t)m * 768 + n; }
        else if (n < 1536) { bias = ldf(bk, n - 768, f);  dst = Kx + (size_t)m * 768 + (n - 768); }
        else               { bias = ldf(bv, n - 1536, f); dst = Vx + (size_t)m * 768 + (n - 1536); }
        *dst = f2bf(acc[h][nt][r] + bias);
      }
}

// ---------------- persistent sequential scan ---------------------------------
// 68 blocks x 384 threads (6 waves). bid<48: gates (4 compute waves K-split-4
// over the block's 64 gate-cols, 2 stager waves stage the 96KB A=[row|h] tile);
// bid<60: kv (4 compute waves, 2 stagers stage the 48KB row tile);
// bid<68: attn (4 batch waves, 2 idle). K-split partials are reduced via an
// LDS f32 buffer laid out [w][b][4m+q] so one ds_read_b128 yields (i,f,g,o).
// NOTE: __launch_bounds__(384, 1) — declaring 2 blocks/CU caps VGPR at 128 and
// scratch-spills Bfr/stg (round-2 regression: 4533 -> 9980 us).
struct ScanParams {
  const void *x, *bih, *bhh, *bk, *bv;
  const u16 *h0b;
  const float *c0f;
  const int* ping;
  const u16 *WihT, *WhhT, *WqkvT;
  const u16 *Qx;
  u16 *Kx, *Vx;
  u16 *rowbuf, *hsb;
  void* out;
  u32 *ctr;       // [0,32,64,96]=arrival lines, [320]=kvctr
  const u32* flag;
};

// drain all waves' stores, then one arrival per block
__device__ __forceinline__ void g_sync_arrive(u32* ctr, int bid) {
  __builtin_amdgcn_s_waitcnt(0);
  __syncthreads();
  if (threadIdx.x == 0)
    __hip_atomic_fetch_add(&ctr[(bid & 3) * 32], 1u, __ATOMIC_RELAXED, __HIP_MEMORY_SCOPE_AGENT);
}
// wave 0 polls the 4 lines directly; broadcasts to other waves via LDS flag
__device__ __forceinline__ void g_wait(u32* ctr, u32 z, u32* sep) {
  if (threadIdx.x < 64) {
    const u32 tgt = PERLINE * z;
    for (;;) {
      u32 mine = tgt;
      if (threadIdx.x < 4)
        mine = __hip_atomic_load(&ctr[threadIdx.x * 32], __ATOMIC_RELAXED, __HIP_MEMORY_SCOPE_AGENT);
      if (__all(mine >= tgt)) break;
      __builtin_amdgcn_s_sleep(1);
    }
    if (threadIdx.x == 0)
      __hip_atomic_store(sep, z, __ATOMIC_RELAXED, __HIP_MEMORY_SCOPE_WORKGROUP);
  } else {
    while (__hip_atomic_load(sep, __ATOMIC_RELAXED, __HIP_MEMORY_SCOPE_WORKGROUP) < z)
      __builtin_amdgcn_s_sleep(1);
  }
  asm volatile("" ::: "memory");
}

__global__ __launch_bounds__(384, 1) void scan_kernel(ScanParams P) {
  // LDS layout (union across roles):
  //  gates: As 0..98304 | P 98304..133120 ([4][32][68] f32) | htile 133120..134144
  //         | biasT 134144..134400
  //  kv:    As 0..49152 | tile 49152..57344 (per-wave [32][32] u16)
  //  attn:  sbuf 0..18432 | sping 18432..26624
  //  all:   sep @134400
  __shared__ __align__(16) unsigned char SH[134448];
  const int bid = blockIdx.x;
  const int tid = threadIdx.x;
  const int wid = tid >> 6;
  const int lane = tid & 63;
  const int l15 = lane & 15, l4 = lane >> 4;
  const u32 f = P.flag[0];
  u32* ctr = P.ctr;
  u32* sep = (u32*)(SH + 134400);
  if (tid == 0) *sep = 0;
  u32 z = 1;

  if (bid < 48) {
    u16* As = (u16*)SH;                       // [32 rows][192 chunks][8], XOR-swizzled
    float* Pp = (float*)(SH + 98304);         // [4][32][68] partial gate sums
    u16* htile = (u16*)(SH + 133120);         // [32][16]
    float* biasT = (float*)(SH + 134144);     // [64] = bias[4m+q]
    const int jb = 16 * bid;                  // block's 16 hidden cols

    if (wid < 4) {
      // ---- compute wave w: all 64 gate-cols, K-range [384w, 384w+384) -------
      const int w = wid;
      const int cq = l15 & 3, cm4 = l15 >> 2;   // col n=16nt+l15 <-> (q=cq, m=4nt+cm4)
      bf16x8 Bfr[12][4];
      {
        const u16* WT = (w < 2) ? P.WihT : P.WhhT;
        const int kbase = 384 * (w & 1);
#pragma unroll
        for (int s = 0; s < 12; ++s)
#pragma unroll
          for (int nt = 0; nt < 4; ++nt) {
            const int colW = 768 * cq + jb + 4 * nt + cm4;
            Bfr[s][nt] = *(const bf16x8*)(WT + (size_t)colW * HID + kbase + 32 * s + 8 * l4);
          }
      }
      if (w == 0) {  // bias table: biasT[4m+q]
        const int m_ = lane >> 2, q_ = lane & 3;
        biasT[lane] = ldf(P.bih, 768 * q_ + jb + m_, f) + ldf(P.bhh, 768 * q_ + jb + m_, f);
      }
      const int cb = 8 * w + (lane >> 3), cm = lane & 7;  // this lane's cells (cb,cm),(cb,cm+8)
      float cst0 = P.c0f[(size_t)cb * HID + jb + cm];
      float cst1 = P.c0f[(size_t)cb * HID + jb + cm + 8];
      g_sync_arrive(ctr, bid); g_wait(ctr, z, sep); ++z;   // prologue: row_0 ready

      for (int i = 0; i < TLEN; ++i) {
        __syncthreads();   // sync1: As staged
        f32x4 zero4 = {0.f, 0.f, 0.f, 0.f};
        f32x4 acc[2][4];
#pragma unroll
        for (int h = 0; h < 2; ++h)
#pragma unroll
          for (int nt = 0; nt < 4; ++nt) acc[h][nt] = zero4;
        const int cbase = 48 * w;
#pragma unroll
        for (int s = 0; s < 12; ++s) {
          const int cc = (cbase + 4 * s + l4) ^ (l15 & 7);
          bf16x8 a0 = *(const bf16x8*)&As[((size_t)l15 * 192 + cc) * 8];
          bf16x8 a1 = *(const bf16x8*)&As[((size_t)(l15 + 16) * 192 + cc) * 8];
#pragma unroll
          for (int nt = 0; nt < 4; ++nt) {
            acc[0][nt] = __builtin_amdgcn_mfma_f32_16x16x32_bf16(a0, Bfr[s][nt], acc[0][nt], 0, 0, 0);
            acc[1][nt] = __builtin_amdgcn_mfma_f32_16x16x32_bf16(a1, Bfr[s][nt], acc[1][nt], 0, 0, 0);
          }
        }
        // partials -> LDS [w][row][16nt + 4cm4 + cq]
        float* Pw = Pp + 2176 * w;
#pragma unroll
        for (int h = 0; h < 2; ++h)
#pragma unroll
          for (int nt = 0; nt < 4; ++nt)
#pragma unroll
            for (int r = 0; r < 4; ++r)
              Pw[(16 * h + 4 * l4 + r) * 68 + 16 * nt + 4 * cm4 + cq] = acc[h][nt][r];
        __syncthreads();   // sync2
        // reduce 4 partials + bias; pointwise for cells (cb,cm),(cb,cm+8)
        f32x4 g0 = *(const f32x4*)&biasT[4 * cm];
        f32x4 g1 = *(const f32x4*)&biasT[4 * (cm + 8)];
#pragma unroll
        for (int w2 = 0; w2 < 4; ++w2) {
          g0 += *(const f32x4*)&Pp[2176 * w2 + 68 * cb + 4 * cm];
          g1 += *(const f32x4*)&Pp[2176 * w2 + 68 * cb + 4 * (cm + 8)];
        }
        cst0 = sigm(g0[1]) * cst0 + sigm(g0[0]) * tanh_(g0[2]);
        cst1 = sigm(g1[1]) * cst1 + sigm(g1[0]) * tanh_(g1[2]);
        float h0v = sigm(g0[3]) * tanh_(cst0);
        float h1v = sigm(g1[3]) * tanh_(cst1);
        htile[cb * 16 + cm] = f2bf(h0v);
        htile[cb * 16 + cm + 8] = f2bf(h1v);
        __syncthreads();   // sync3 (flusher wave writes hsb)
        g_sync_arrive(ctr, bid);
        // out stores off the critical path (drained by next step's arrive)
        const size_t o1 = (size_t)i * NB * HID + (size_t)cb * HID + jb + cm;
        if (f) { float* O = (float*)P.out; O[o1] = h0v; O[o1 + 8] = h1v; }
        else   { u16*   O = (u16*)P.out;   O[o1] = f2bf(h0v); O[o1 + 8] = f2bf(h1v); }
        if (i == TLEN - 1) {
          const size_t oh = (size_t)TLEN * NB * HID + (size_t)cb * HID + jb + cm;
          const size_t oc = (size_t)(TLEN + 1) * NB * HID + (size_t)cb * HID + jb + cm;
          if (f) { float* O = (float*)P.out; O[oh] = h0v; O[oh + 8] = h1v; O[oc] = cst0; O[oc + 8] = cst1; }
          else   { u16*   O = (u16*)P.out;   O[oh] = f2bf(h0v); O[oh + 8] = f2bf(h1v);
                   O[oc] = f2bf(cst0); O[oc + 8] = f2bf(cst1); }
        }
        g_wait(ctr, z, sep); ++z;
      }
    } else {
      // ---- stager waves (wid 4,5): stage A=[row|h] 32x1536 bf16 into LDS ----
      const int stq = (wid - 4) * 64 + lane;   // 0..127
      g_sync_arrive(ctr, bid); g_wait(ctr, z, sep); ++z;   // prologue

      for (int i = 0; i < TLEN; ++i) {
        const u16* rowp = P.rowbuf + (size_t)(i & 1) * NB * HID;
        const u16* hp = (i == 0) ? P.h0b : (P.hsb + (size_t)((i - 1) & 1) * NB * HID);
        bf16x8 stg[48];
#pragma unroll
        for (int j = 0; j < 48; ++j) {
          const int g = stq + 128 * j;
          const int r = g / 192, c = g - r * 192;
          const u16* src = (c < 96) ? (rowp + (size_t)r * HID + c * 8)
                                    : (hp + (size_t)r * HID + (c - 96) * 8);
          stg[j] = cld128(src);
        }
#pragma unroll
        for (int j = 0; j < 48; ++j) {
          const int g = stq + 128 * j;
          const int r = g / 192, c = g - r * 192;
          *(bf16x8*)&As[((size_t)r * 192 + (c ^ (r & 7))) * 8] = stg[j];
        }
        __syncthreads();   // sync1
        __syncthreads();   // sync2
        __syncthreads();   // sync3: htile complete
        if (wid == 4) {    // flush h tile -> hsb (global, coherent)
#pragma unroll
          for (int k = 0; k < 2; ++k) {
            const int idx = lane + 64 * k;
            const int b = idx >> 2, part = idx & 3;
            u64 hv; __builtin_memcpy(&hv, &htile[b * 16 + 4 * part], 8);
            cst64(P.hsb + (size_t)(i & 1) * NB * HID + (size_t)b * HID + jb + 4 * part, hv);
          }
        }
        g_sync_arrive(ctr, bid);
        g_wait(ctr, z, sep); ++z;
      }
    }
  } else if (bid < 60) {
    // ------- k/v projection: 4 compute waves (32 cols each), 2 stagers --------
    u16* As = (u16*)SH;                                  // [32][96 chunks][8]
    u16* tile = (u16*)(SH + 49152) + wid * 1024;         // [32][32] per compute wave
    if (wid < 4) {
      const int kw = (bid - 48) * 4 + wid;
      const int col0 = 32 * kw;
      const bool isV = (col0 >= 768);
      const u16* Wt = P.WqkvT + (size_t)(768 + col0) * HID;
      const int oc0 = isV ? (col0 - 768) : col0;
      u16* obase = isV ? P.Vx : P.Kx;
      const void* bias_src = isV ? P.bv : P.bk;
      const float bias0 = ldf(bias_src, oc0 + l15, f);
      const float bias1 = ldf(bias_src, oc0 + 16 + l15, f);
      bf16x8 Bfr[48];
#pragma unroll
      for (int s = 0; s < 24; ++s) {
        int k = 32 * s + 8 * l4;
        Bfr[2 * s]     = *(const bf16x8*)(Wt + (size_t)l15 * HID + k);
        Bfr[2 * s + 1] = *(const bf16x8*)(Wt + (size_t)(16 + l15) * HID + k);
      }
      g_sync_arrive(ctr, bid); g_wait(ctr, z, sep); ++z;   // prologue

      for (int i = 0; i < TLEN; ++i) {
        __syncthreads();   // As staged
        f32x4 a00 = {0.f,0.f,0.f,0.f}, a01 = {0.f,0.f,0.f,0.f};
        f32x4 a10 = {0.f,0.f,0.f,0.f}, a11 = {0.f,0.f,0.f,0.f};
#pragma unroll
        for (int s = 0; s < 24; ++s) {
          const int cc = (4 * s + l4) ^ (l15 & 7);
          bf16x8 r0 = *(const bf16x8*)&As[((size_t)l15 * 96 + cc) * 8];
          bf16x8 r1 = *(const bf16x8*)&As[((size_t)(l15 + 16) * 96 + cc) * 8];
          a00 = __builtin_amdgcn_mfma_f32_16x16x32_bf16(r0, Bfr[2 * s],     a00, 0, 0, 0);
          a01 = __builtin_amdgcn_mfma_f32_16x16x32_bf16(r0, Bfr[2 * s + 1], a01, 0, 0, 0);
          a10 = __builtin_amdgcn_mfma_f32_16x16x32_bf16(r1, Bfr[2 * s],     a10, 0, 0, 0);
          a11 = __builtin_amdgcn_mfma_f32_16x16x32_bf16(r1, Bfr[2 * s + 1], a11, 0, 0, 0);
        }
#pragma unroll
        for (int r = 0; r < 4; ++r) {
          int b0 = 4 * l4 + r;
          tile[b0 * 32 + l15]             = f2bf(a00[r] + bias0);
          tile[b0 * 32 + 16 + l15]        = f2bf(a01[r] + bias1);
          tile[(16 + b0) * 32 + l15]      = f2bf(a10[r] + bias0);
          tile[(16 + b0) * 32 + 16 + l15] = f2bf(a11[r] + bias1);
        }
        wfence();
        {
          u16* ob = obase + (size_t)i * NB * HID + oc0;
          const int row = lane >> 1, ch = (lane & 1) * 16;
#pragma unroll
          for (int q = 0; q < 4; ++q) {
            u64 w8; __builtin_memcpy(&w8, &tile[row * 32 + ch + 4 * q], 8);
            cst64(ob + (size_t)row * HID + ch + 4 * q, w8);
          }
        }
        // drain, publish kv-row-complete, arrive
        __builtin_amdgcn_s_waitcnt(0);
        __syncthreads();
        if (tid == 0) {
          __hip_atomic_fetch_add(&ctr[320], 1u, __ATOMIC_RELAXED, __HIP_MEMORY_SCOPE_AGENT);
          __hip_atomic_fetch_add(&ctr[(bid & 3) * 32], 1u, __ATOMIC_RELAXED, __HIP_MEMORY_SCOPE_AGENT);
        }
        g_wait(ctr, z, sep); ++z;
      }
    } else {
      // ---- stager waves: stage row (32 x 768 bf16) into LDS -----------------
      const int stq = (wid - 4) * 64 + lane;   // 0..127
      g_sync_arrive(ctr, bid); g_wait(ctr, z, sep); ++z;   // prologue

      for (int i = 0; i < TLEN; ++i) {
        const u16* rowp = P.rowbuf + (size_t)(i & 1) * NB * HID;
        bf16x8 stg[24];
#pragma unroll
        for (int j = 0; j < 24; ++j) {
          const int g = stq + 128 * j;
          const int r = g / 96, c = g - r * 96;
          stg[j] = cld128(rowp + (size_t)r * HID + c * 8);
        }
#pragma unroll
        for (int j = 0; j < 24; ++j) {
          const int g = stq + 128 * j;
          const int r = g / 96, c = g - r * 96;
          *(bf16x8*)&As[((size_t)r * 96 + (c ^ (r & 7))) * 8] = stg[j];
        }
        __syncthreads();   // As staged
        __builtin_amdgcn_s_waitcnt(0);
        __syncthreads();
        g_wait(ctr, z, sep); ++z;
      }
    }
  } else {
    // ------- attention: waves 0-3 = one batch each; waves 4,5 idle ------------
    const int b = (bid - 60) * 4 + wid;
    u16* sb = (u16*)SH + wid * 2304;                     // [3][768]
    int* spng = (int*)(SH + 18432) + wid * 512;
    if (wid < 4) {
      for (int j = lane; j < TLEN; j += 64) spng[j] = P.ping[(size_t)b * TLEN + j];
      {  // prologue: row_0 = x[0] (t=0 mask false)
        const size_t xoff = (size_t)b * HID + 12 * lane;
        u16* orow = P.rowbuf + (size_t)b * HID + 12 * lane;
#pragma unroll
        for (int q = 0; q < 3; ++q) {
          u16 e[4];
#pragma unroll
          for (int t2 = 0; t2 < 4; ++t2) e[t2] = ldbf(P.x, xoff + 4 * q + t2, f);
          u64 w8; __builtin_memcpy(&w8, e, 8);
          cst64(orow + 4 * q, w8);
        }
      }
    }
    g_sync_arrive(ctr, bid); g_wait(ctr, z, sep); ++z;   // prologue

    for (int i = 0; i < TLEN; ++i) {
      if (wid < 4 && i < TLEN - 1) {
        const int t = i + 1;
        const int p = spng[t];
        u16* orow = P.rowbuf + (size_t)(t & 1) * NB * HID + (size_t)b * HID;
        if (p == 0) {  // mask false -> row = x[t]
          const size_t xoff = ((size_t)t * NB + b) * HID + 12 * lane;
#pragma unroll
          for (int q = 0; q < 3; ++q) {
            u16 e[4];
#pragma unroll
            for (int t2 = 0; t2 < 4; ++t2) e[t2] = ldbf(P.x, xoff + 4 * q + t2, f);
            u64 w8; __builtin_memcpy(&w8, e, 8);
            cst64(orow + 12 * lane + 4 * q, w8);
          }
        } else {
          const int idx = p - 1;
          // q / right-key / right-value: static rows, plain loads, issued early
          const u16* qp = P.Qx + ((size_t)t * NB + b) * HID;  // never rewritten
          const u16* kR = P.Kx + ((size_t)t * NB + b) * HID;  // untouched until interval t
          const u16* vR = P.Vx + ((size_t)t * NB + b) * HID;
          float qv[12], krv[12], vrv[12];
#pragma unroll
          for (int j = 0; j < 12; ++j) {
            qv[j]  = bf2f(qp[64 * j + lane]);
            krv[j] = bf2f(kR[64 * j + lane]);
            vrv[j] = bf2f(vR[64 * j + lane]);
          }
          if (idx == i) {  // produced this interval: wait for the 12 kv blocks
            while (__hip_atomic_load(&ctr[320], __ATOMIC_RELAXED, __HIP_MEMORY_SCOPE_AGENT) <
                   12u * (u32)(i + 1)) {
              __builtin_amdgcn_s_sleep(2);
            }
            asm volatile("" ::: "memory");
          }
          const u16* kL = P.Kx + ((size_t)idx * NB + b) * HID;
          const u16* vL = P.Vx + ((size_t)idx * NB + b) * HID;
#pragma unroll
          for (int q = 0; q < 3; ++q) {
            *(u64*)&sb[12 * lane + 4 * q]       = cld64(kL + 12 * lane + 4 * q);
            *(u64*)&sb[768 + 12 * lane + 4 * q] = cld64(vL + 12 * lane + 4 * q);
          }
          wfence();
          float d0[12], d1[12];
#pragma unroll
          for (int j = 0; j < 12; ++j) {
            d0[j] = qv[j] * bf2f(sb[64 * j + lane]);
            d1[j] = qv[j] * krv[j];
          }
#pragma unroll
          for (int m = 32; m > 0; m >>= 1) {
#pragma unroll
            for (int j = 0; j < 12; ++j) {
              d0[j] += __shfl_xor(d0[j], m);
              d1[j] += __shfl_xor(d1[j], m);
            }
          }
#pragma unroll
          for (int j = 0; j < 12; ++j) {
            float pw0 = sigm((d0[j] - d1[j]) * 0.125f);  // softmax over 2 keys
            float ov = pw0 * bf2f(sb[768 + 64 * j + lane]) + (1.0f - pw0) * vrv[j];
            sb[1536 + 64 * j + lane] = f2bf(ov);
          }
          wfence();
#pragma unroll
          for (int q = 0; q < 3; ++q) {
            u64 w8; __builtin_memcpy(&w8, &sb[1536 + 12 * lane + 4 * q], 8);
            cst64(orow + 12 * lane + 4 * q, w8);
          }
        }
      }
      g_sync_arrive(ctr, bid); g_wait(ctr, z, sep); ++z;
    }
  }
}

extern "C" void kernel_launch(void* const* d_in, const int* in_sizes, int n_in,
                              void* d_out, int out_size, void* d_ws, size_t ws_size,
                              hipStream_t stream) {
  const void* x   = d_in[0];
  const int* ping = (const int*)d_in[1];
  const void* h0  = d_in[2];
  const void* c0  = d_in[3];
  const void* wih = d_in[4];
  const void* whh = d_in[5];
  const void* bih = d_in[6];
  const void* bhh = d_in[7];
  const void* wq  = d_in[8];
  const void* bq  = d_in[9];
  const void* wk  = d_in[10];
  const void* bk  = d_in[11];
  const void* wv  = d_in[12];
  const void* bv  = d_in[13];
  (void)in_sizes; (void)n_in; (void)out_size; (void)ws_size;  // needs ~90 MB ws

  char* ws = (char*)d_ws;
  size_t off = 0;
  auto walloc = [&](size_t b) { char* p = ws + off; off += (b + 255) & ~(size_t)255; return p; };
  u32* ctr    = (u32*)walloc(2048);
  u32* flag   = ctr + 400;  // clear of lines 0..96, kvctr 320
  u16* WqkvT  = (u16*)walloc((size_t)2304 * 768 * 2);
  u16* WihT   = (u16*)walloc((size_t)3072 * 768 * 2);
  u16* WhhT   = (u16*)walloc((size_t)3072 * 768 * 2);
  u16* Qx     = (u16*)walloc((size_t)TLEN * NB * HID * 2);
  u16* Kx     = (u16*)walloc((size_t)TLEN * NB * HID * 2);
  u16* Vx     = (u16*)walloc((size_t)TLEN * NB * HID * 2);
  u16* rowbuf = (u16*)walloc((size_t)2 * NB * HID * 2);
  u16* h0b    = (u16*)walloc((size_t)NB * HID * 2);
  float* c0f  = (float*)walloc((size_t)NB * HID * 4);
  u16* hsb    = (u16*)walloc((size_t)2 * NB * HID * 2);

  hipMemsetAsync(ctr, 0, 2048, stream);
  prologue<<<1, 256, 0, stream>>>(x, h0, c0, flag, h0b, c0f);
  transpose_any<<<dim3(12, 12), 256, 0, stream>>>(wq, WqkvT, 768, 768, flag);
  transpose_any<<<dim3(12, 12), 256, 0, stream>>>(wk, WqkvT + (size_t)768 * 768, 768, 768, flag);
  transpose_any<<<dim3(12, 12), 256, 0, stream>>>(wv, WqkvT + (size_t)1536 * 768, 768, 768, flag);
  transpose_any<<<dim3(48, 12), 256, 0, stream>>>(wih, WihT, 768, 3072, flag);
  transpose_any<<<dim3(48, 12), 256, 0, stream>>>(whh, WhhT, 768, 3072, flag);
  qkv_gemm<<<dim3(128, 18), 256, 0, stream>>>(x, WqkvT, bq, bk, bv, Qx, Kx, Vx, flag);

  ScanParams P;
  P.x = x; P.bih = bih; P.bhh = bhh; P.bk = bk; P.bv = bv;
  P.h0b = h0b; P.c0f = c0f;
  P.ping = ping;
  P.WihT = WihT; P.WhhT = WhhT; P.WqkvT = WqkvT;
  P.Qx = Qx; P.Kx = Kx; P.Vx = Vx;
  P.rowbuf = rowbuf; P.hsb = hsb;
  P.out = d_out;
  P.ctr = ctr; P.flag = flag;
  scan_kernel<<<dim3(NBLK), dim3(384), 0, stream>>>(P);
}

// Round 4
// 3878.949 us; speedup vs baseline: 2.6844x; 2.6683x over previous
//
#include <hip/hip_runtime.h>
#include <hip/hip_bf16.h>

#define TLEN 512
#define NB   32
#define HID  768
#define NBLK 68

typedef __attribute__((ext_vector_type(8))) short bf16x8;
typedef __attribute__((ext_vector_type(4))) float f32x4;
typedef unsigned short u16;
typedef unsigned int u32;
typedef unsigned long long u64;

__device__ __forceinline__ float bf2f(u16 u) {
  u32 t = ((u32)u) << 16; float f; __builtin_memcpy(&f, &t, 4); return f;
}
__device__ __forceinline__ u16 f2bf(float f) {
  u32 t; __builtin_memcpy(&t, &f, 4);
  u32 r = t + 0x7FFFu + ((t >> 16) & 1u);
  return (u16)(r >> 16);
}
// dual-dtype scalar loads: f!=0 -> input buffer is fp32, else packed bf16
__device__ __forceinline__ u16 ldbf(const void* p, size_t i, u32 f) {
  return f ? f2bf(((const float*)p)[i]) : ((const u16*)p)[i];
}
__device__ __forceinline__ float ldf(const void* p, size_t i, u32 f) {
  return f ? ((const float*)p)[i] : bf2f(((const u16*)p)[i]);
}
__device__ __forceinline__ float sigm(float x) { return 1.0f / (1.0f + __expf(-x)); }
__device__ __forceinline__ float tanh_(float x) { return 1.0f - 2.0f / (1.0f + __expf(2.0f * x)); }

// ---- agent-scope (cross-XCD coherent) accesses ----
__device__ __forceinline__ u64 cld64(const u16* p) {
  return __hip_atomic_load((const u64*)p, __ATOMIC_RELAXED, __HIP_MEMORY_SCOPE_AGENT);
}
__device__ __forceinline__ void cst64(u16* p, u64 v) {
  __hip_atomic_store((u64*)p, v, __ATOMIC_RELAXED, __HIP_MEMORY_SCOPE_AGENT);
}
__device__ __forceinline__ bf16x8 cld128(const u16* p) {
  union { u64 q[2]; bf16x8 v; } u;
  u.q[0] = cld64(p); u.q[1] = cld64(p + 4);
  return u.v;
}
// wave-internal LDS fence (lockstep wave64: write->fence->read is safe)
__device__ __forceinline__ void wfence() {
  asm volatile("s_waitcnt lgkmcnt(0)" ::: "memory");
}

// ---------------- prologue: dtype sniff + h0/c0 conversion -------------------
__global__ __launch_bounds__(256) void prologue(const void* __restrict__ x,
                                                const void* __restrict__ h0,
                                                const void* __restrict__ c0,
                                                u32* __restrict__ flag,
                                                u16* __restrict__ h0b,
                                                float* __restrict__ c0f) {
  __shared__ u32 sflag;
  if (threadIdx.x == 0) {
    const u32* w = (const u32*)x;
    int cnt = 0;
    for (int m = 0; m < 256; ++m) {
      u32 e = ((w[m] & 0xFFFFu) >> 7) & 0xFFu;
      cnt += (e >= 100u && e <= 140u) ? 1 : 0;
    }
    sflag = (cnt >= 128) ? 0u : 1u;  // 1 = fp32 inputs
    flag[0] = sflag;
  }
  __syncthreads();
  const u32 f = sflag;
  for (int i = threadIdx.x; i < NB * HID; i += 256) {
    h0b[i] = ldbf(h0, i, f);
    c0f[i] = ldf(c0, i, f);
  }
}

// ---------------- transpose (R x C row-major -> C x R, emits bf16) ----------
__global__ __launch_bounds__(256) void transpose_any(const void* __restrict__ in,
                                                     u16* __restrict__ out, int R, int C,
                                                     const u32* __restrict__ flag) {
  const u32 f = flag[0];
  __shared__ u16 tile[64][65];
  int c0 = blockIdx.x * 64, r0 = blockIdx.y * 64;
  int tx = threadIdx.x & 63, ty = threadIdx.x >> 6;
#pragma unroll
  for (int j = 0; j < 16; ++j) {
    int r = ty + 4 * j;
    tile[r][tx] = ldbf(in, (size_t)(r0 + r) * C + c0 + tx, f);
  }
  __syncthreads();
#pragma unroll
  for (int j = 0; j < 16; ++j) {
    int r = ty + 4 * j;
    out[(size_t)(c0 + r) * R + r0 + tx] = tile[tx][r];
  }
}

// ---------------- QKV precompute: [16384 x 768] @ [768 x 2304] --------------
__global__ __launch_bounds__(256) void qkv_gemm(const void* __restrict__ X, const u16* __restrict__ WT,
                                                const void* __restrict__ bq, const void* __restrict__ bk,
                                                const void* __restrict__ bv,
                                                u16* __restrict__ Qx, u16* __restrict__ Kx,
                                                u16* __restrict__ Vx, const u32* __restrict__ flag) {
  const u32 f = flag[0];
  __shared__ __align__(16) u16 As[128][40];
  __shared__ __align__(16) u16 Bs[128][40];
  const int m0 = blockIdx.x * 128;
  const int n0 = blockIdx.y * 128;
  const int tid = threadIdx.x;
  const int lane = tid & 63, w = tid >> 6;
  const int l15 = lane & 15, l4 = lane >> 4;
  f32x4 zero4 = {0.f, 0.f, 0.f, 0.f};
  f32x4 acc[2][8];
#pragma unroll
  for (int h = 0; h < 2; ++h)
#pragma unroll
    for (int nt = 0; nt < 8; ++nt) acc[h][nt] = zero4;
  const int srow = tid >> 1, skp = (tid & 1) * 16;
  for (int k0 = 0; k0 < 768; k0 += 32) {
    __syncthreads();
    if (f) {
      const float* Xf = (const float*)X + (size_t)(m0 + srow) * 768 + k0 + skp;
#pragma unroll
      for (int q = 0; q < 16; ++q) As[srow][skp + q] = f2bf(Xf[q]);
    } else {
      const u16* Xh = (const u16*)X + (size_t)(m0 + srow) * 768 + k0 + skp;
      *(bf16x8*)&As[srow][skp]     = *(const bf16x8*)(Xh);
      *(bf16x8*)&As[srow][skp + 8] = *(const bf16x8*)(Xh + 8);
    }
    *(bf16x8*)&Bs[srow][skp]     = *(const bf16x8*)(WT + (size_t)(n0 + srow) * 768 + k0 + skp);
    *(bf16x8*)&Bs[srow][skp + 8] = *(const bf16x8*)(WT + (size_t)(n0 + srow) * 768 + k0 + skp + 8);
    __syncthreads();
    const int kl = 8 * l4;
    bf16x8 a0 = *(const bf16x8*)&As[32 * w + l15][kl];
    bf16x8 a1 = *(const bf16x8*)&As[32 * w + 16 + l15][kl];
#pragma unroll
    for (int nt = 0; nt < 8; ++nt) {
      bf16x8 b = *(const bf16x8*)&Bs[16 * nt + l15][kl];
      acc[0][nt] = __builtin_amdgcn_mfma_f32_16x16x32_bf16(a0, b, acc[0][nt], 0, 0, 0);
      acc[1][nt] = __builtin_amdgcn_mfma_f32_16x16x32_bf16(a1, b, acc[1][nt], 0, 0, 0);
    }
  }
#pragma unroll
  for (int h = 0; h < 2; ++h)
#pragma unroll
    for (int nt = 0; nt < 8; ++nt)
#pragma unroll
      for (int r = 0; r < 4; ++r) {
        const int m = m0 + 32 * w + 16 * h + 4 * l4 + r;
        const int n = n0 + 16 * nt + l15;
        float bias; u16* dst;
        if (n < 768)       { bias = ldf(bq, n, f);        dst = Qx + (size_t)m * 768 + n; }
        else if (n < 1536) { bias = ldf(bk, n - 768, f);  dst = Kx + (size_t)m * 768 + (n - 768); }
        else               { bias = ldf(bv, n - 1536, f); dst = Vx + (size_t)m * 768 + (n - 1536); }
        *dst = f2bf(acc[h][nt][r] + bias);
      }
}

// ---------------- persistent sequential scan ---------------------------------
// 68 blocks x 256 threads (4 waves; 256-thread blocks get the full 256-VGPR +
// AGPR budget — 384-thread blocks cap at 128 and spill, rounds 2/3).
// bid<48: gates — 4 compute waves, K-split-4 (each wave: all 64 gate-cols of
//   this block's 16 hidden cols, K-range 384w), partials reduced via LDS;
//   staging of A=[row|h] (96KB) done cooperatively by the same 4 waves.
// bid<60: kv — K-split-2 (wave = 64-col group x K-half), partial-reduce in
//   LDS, reduce+store direct to Kx/Vx.
// bid<68: attn — 4 waves, one batch each.
// Barrier: per-block stamp-store slots (no RMW); wave0 polls all 68 slots.
struct ScanParams {
  const void *x, *bih, *bhh, *bk, *bv;
  const u16 *h0b;
  const float *c0f;
  const int* ping;
  const u16 *WihT, *WhhT, *WqkvT;
  const u16 *Qx;
  u16 *Kx, *Vx;
  u16 *rowbuf, *hsb;
  void* out;
  u32 *ctr;       // [0..67] = per-block stamp slots
  const u32* flag;
};

// drain own stores, block-sync, stamp this block's slot with z
__device__ __forceinline__ void g_arrive(u32* slots, int bid, u32 z) {
  __builtin_amdgcn_s_waitcnt(0);
  __syncthreads();
  if (threadIdx.x == 0)
    __hip_atomic_store(&slots[bid], z, __ATOMIC_RELAXED, __HIP_MEMORY_SCOPE_AGENT);
}
// wave 0 polls all 68 slots (coalesced lane-load); broadcasts via LDS flag
__device__ __forceinline__ void g_wait(u32* slots, u32 z, u32* sep) {
  if (threadIdx.x < 64) {
    const int lane = threadIdx.x;
    for (;;) {
      u32 a = __hip_atomic_load(&slots[lane], __ATOMIC_RELAXED, __HIP_MEMORY_SCOPE_AGENT);
      u32 b = (lane < 4) ? __hip_atomic_load(&slots[64 + lane], __ATOMIC_RELAXED, __HIP_MEMORY_SCOPE_AGENT)
                         : z;
      if (__all((a >= z) & (b >= z))) break;
      __builtin_amdgcn_s_sleep(1);
    }
    if (threadIdx.x == 0)
      __hip_atomic_store(sep, z, __ATOMIC_RELAXED, __HIP_MEMORY_SCOPE_WORKGROUP);
  } else {
    while (__hip_atomic_load(sep, __ATOMIC_RELAXED, __HIP_MEMORY_SCOPE_WORKGROUP) < z)
      __builtin_amdgcn_s_sleep(1);
  }
  asm volatile("" ::: "memory");
}

__global__ __launch_bounds__(256, 1) void scan_kernel(ScanParams P) {
  // LDS layout (union across roles):
  //  gates: As 0..98304 | Pp 98304..133120 ([4][32][68] f32) | htile 133120..134144
  //         | biasT 134144..134400
  //  kv:    As 0..49152 | Pk 49152..82944 ([2][32][132] f32)
  //  attn:  sbuf 0..18432 | sping 18432..26624
  //  all:   sep @134400
  __shared__ __align__(16) unsigned char SH[134416];
  const int bid = blockIdx.x;
  const int tid = threadIdx.x;
  const int wid = tid >> 6;
  const int lane = tid & 63;
  const int l15 = lane & 15, l4 = lane >> 4;
  const u32 f = P.flag[0];
  u32* ctr = P.ctr;
  u32* sep = (u32*)(SH + 134400);
  if (tid == 0) *sep = 0;
  u32 z = 1;

  if (bid < 48) {
    u16* As = (u16*)SH;                       // [32 rows][192 chunks][8], XOR-swizzled
    float* Pp = (float*)(SH + 98304);         // [4][32][68] partial gate sums
    u16* htile = (u16*)(SH + 133120);         // [32][16]
    float* biasT = (float*)(SH + 134144);     // [64] = bias[4m+q]
    const int jb = 16 * bid;                  // block's 16 hidden cols
    const int w = wid;
    const int cq = l15 & 3, cm4 = l15 >> 2;   // col n=16nt+l15 <-> (q=cq, m=4nt+cm4)
    // ---- B fragments: wave w covers K-range [384*(w&1), +384) of Wih (w<2) or Whh ----
    bf16x8 Bfr[12][4];
    {
      const u16* WT = (w < 2) ? P.WihT : P.WhhT;
      const int kbase = 384 * (w & 1);
#pragma unroll
      for (int s = 0; s < 12; ++s)
#pragma unroll
        for (int nt = 0; nt < 4; ++nt) {
          const int colW = 768 * cq + jb + 4 * nt + cm4;
          Bfr[s][nt] = *(const bf16x8*)(WT + (size_t)colW * HID + kbase + 32 * s + 8 * l4);
        }
    }
    if (w == 0) {  // bias table: biasT[4m+q]
      const int m_ = lane >> 2, q_ = lane & 3;
      biasT[lane] = ldf(P.bih, 768 * q_ + jb + m_, f) + ldf(P.bhh, 768 * q_ + jb + m_, f);
    }
    const int cb = 8 * w + (lane >> 3), cm = lane & 7;  // this lane's cells (cb,cm),(cb,cm+8)
    float cst0 = P.c0f[(size_t)cb * HID + jb + cm];
    float cst1 = P.c0f[(size_t)cb * HID + jb + cm + 8];
    g_arrive(ctr, bid, z); g_wait(ctr, z, sep); ++z;   // prologue: row_0 ready

    for (int i = 0; i < TLEN; ++i) {
      const u16* rowp = P.rowbuf + (size_t)(i & 1) * NB * HID;
      const u16* hp = (i == 0) ? P.h0b : (P.hsb + (size_t)((i - 1) & 1) * NB * HID);
      // ---- cooperative staging of A=[row|h] (32x1536 bf16), 2 low-live rounds ----
#pragma unroll
      for (int half = 0; half < 2; ++half) {
        bf16x8 stg[12];
#pragma unroll
        for (int j = 0; j < 12; ++j) {
          const int g2 = tid + 256 * (12 * half + j);
          const int r = g2 / 192, c = g2 - r * 192;
          const u16* src = (c < 96) ? (rowp + (size_t)r * HID + c * 8)
                                    : (hp + (size_t)r * HID + (c - 96) * 8);
          stg[j] = cld128(src);
        }
#pragma unroll
        for (int j = 0; j < 12; ++j) {
          const int g2 = tid + 256 * (12 * half + j);
          const int r = g2 / 192, c = g2 - r * 192;
          *(bf16x8*)&As[((size_t)r * 192 + (c ^ (r & 7))) * 8] = stg[j];
        }
      }
      __syncthreads();   // sync1: As staged
      f32x4 zero4 = {0.f, 0.f, 0.f, 0.f};
      f32x4 acc[2][4];
#pragma unroll
      for (int h = 0; h < 2; ++h)
#pragma unroll
        for (int nt = 0; nt < 4; ++nt) acc[h][nt] = zero4;
      const int cbase = 48 * w;
#pragma unroll
      for (int s = 0; s < 12; ++s) {
        const int cc = (cbase + 4 * s + l4) ^ (l15 & 7);
        bf16x8 a0 = *(const bf16x8*)&As[((size_t)l15 * 192 + cc) * 8];
        bf16x8 a1 = *(const bf16x8*)&As[((size_t)(l15 + 16) * 192 + cc) * 8];
#pragma unroll
        for (int nt = 0; nt < 4; ++nt) {
          acc[0][nt] = __builtin_amdgcn_mfma_f32_16x16x32_bf16(a0, Bfr[s][nt], acc[0][nt], 0, 0, 0);
          acc[1][nt] = __builtin_amdgcn_mfma_f32_16x16x32_bf16(a1, Bfr[s][nt], acc[1][nt], 0, 0, 0);
        }
      }
      // partials -> LDS [w][row][16nt + 4cm4 + cq]
      float* Pw = Pp + 2176 * w;
#pragma unroll
      for (int h = 0; h < 2; ++h)
#pragma unroll
        for (int nt = 0; nt < 4; ++nt)
#pragma unroll
          for (int r = 0; r < 4; ++r)
            Pw[(16 * h + 4 * l4 + r) * 68 + 16 * nt + 4 * cm4 + cq] = acc[h][nt][r];
      __syncthreads();   // sync2
      // reduce 4 partials + bias; pointwise for cells (cb,cm),(cb,cm+8)
      f32x4 g0 = *(const f32x4*)&biasT[4 * cm];
      f32x4 g1 = *(const f32x4*)&biasT[4 * (cm + 8)];
#pragma unroll
      for (int w2 = 0; w2 < 4; ++w2) {
        g0 += *(const f32x4*)&Pp[2176 * w2 + 68 * cb + 4 * cm];
        g1 += *(const f32x4*)&Pp[2176 * w2 + 68 * cb + 4 * (cm + 8)];
      }
      cst0 = sigm(g0[1]) * cst0 + sigm(g0[0]) * tanh_(g0[2]);
      cst1 = sigm(g1[1]) * cst1 + sigm(g1[0]) * tanh_(g1[2]);
      float h0v = sigm(g0[3]) * tanh_(cst0);
      float h1v = sigm(g1[3]) * tanh_(cst1);
      htile[cb * 16 + cm] = f2bf(h0v);
      htile[cb * 16 + cm + 8] = f2bf(h1v);
      wfence();          // same-wave htile rows complete
      if (lane < 32) {   // wave w flushes its own 8 batch-rows (16 cols = 4x8B)
        const int b = 8 * w + (lane >> 2), part = lane & 3;
        u64 hv; __builtin_memcpy(&hv, &htile[b * 16 + 4 * part], 8);
        cst64(P.hsb + (size_t)(i & 1) * NB * HID + (size_t)b * HID + jb + 4 * part, hv);
      }
      g_arrive(ctr, bid, z);
      // out stores off the critical path (drained by next step's arrive)
      const size_t o1 = (size_t)i * NB * HID + (size_t)cb * HID + jb + cm;
      if (f) { float* O = (float*)P.out; O[o1] = h0v; O[o1 + 8] = h1v; }
      else   { u16*   O = (u16*)P.out;   O[o1] = f2bf(h0v); O[o1 + 8] = f2bf(h1v); }
      if (i == TLEN - 1) {
        const size_t oh = (size_t)TLEN * NB * HID + (size_t)cb * HID + jb + cm;
        const size_t oc = (size_t)(TLEN + 1) * NB * HID + (size_t)cb * HID + jb + cm;
        if (f) { float* O = (float*)P.out; O[oh] = h0v; O[oh + 8] = h1v; O[oc] = cst0; O[oc + 8] = cst1; }
        else   { u16*   O = (u16*)P.out;   O[oh] = f2bf(h0v); O[oh + 8] = f2bf(h1v);
                 O[oc] = f2bf(cst0); O[oc + 8] = f2bf(cst1); }
      }
      g_wait(ctr, z, sep); ++z;
    }
  } else if (bid < 60) {
    // ------- k/v projection: K-split-2, wave = (64-col group g) x (K-half kh) --
    u16* As = (u16*)SH;                                  // [32][96 chunks][8]
    float* Pk = (float*)(SH + 49152);                    // [2][32][132]
    const int kb = bid - 48;
    const int col0 = 128 * kb;                           // within [K|V] concat (1536)
    const bool isV = kb >= 6;
    const int oc0 = col0 - (isV ? 768 : 0);
    u16* obase = isV ? P.Vx : P.Kx;
    const void* bias_src = isV ? P.bv : P.bk;
    const int g = wid & 1, kh = wid >> 1;
    const u16* Wt = P.WqkvT + (size_t)(768 + col0 + 64 * g) * HID;
    const int kbase = 384 * kh;
    bf16x8 Bfr[12][4];
#pragma unroll
    for (int s = 0; s < 12; ++s)
#pragma unroll
      for (int nt = 0; nt < 4; ++nt)
        Bfr[s][nt] = *(const bf16x8*)(Wt + (size_t)(16 * nt + l15) * HID + kbase + 32 * s + 8 * l4);
    // reduce-phase personal constants: thread -> (rrow, 16-col chunk rc)
    const int rrow = tid >> 3, rc = (tid & 7) * 16;
    float biasr[16];
#pragma unroll
    for (int e = 0; e < 16; ++e) biasr[e] = ldf(bias_src, oc0 + rc + e, f);
    g_arrive(ctr, bid, z); g_wait(ctr, z, sep); ++z;   // prologue

    for (int i = 0; i < TLEN; ++i) {
      const u16* rowp = P.rowbuf + (size_t)(i & 1) * NB * HID;
      // ---- cooperative staging of row (32x768 bf16), 2 rounds ----
#pragma unroll
      for (int half = 0; half < 2; ++half) {
        bf16x8 stg[6];
#pragma unroll
        for (int j = 0; j < 6; ++j) {
          const int g2 = tid + 256 * (6 * half + j);
          const int r = g2 / 96, c = g2 - r * 96;
          stg[j] = cld128(rowp + (size_t)r * HID + c * 8);
        }
#pragma unroll
        for (int j = 0; j < 6; ++j) {
          const int g2 = tid + 256 * (6 * half + j);
          const int r = g2 / 96, c = g2 - r * 96;
          *(bf16x8*)&As[((size_t)r * 96 + (c ^ (r & 7))) * 8] = stg[j];
        }
      }
      __syncthreads();   // As staged
      f32x4 zero4 = {0.f, 0.f, 0.f, 0.f};
      f32x4 acc[2][4];
#pragma unroll
      for (int t = 0; t < 2; ++t)
#pragma unroll
        for (int nt = 0; nt < 4; ++nt) acc[t][nt] = zero4;
      const int cbase = 48 * kh;
#pragma unroll
      for (int s = 0; s < 12; ++s) {
        const int cc = (cbase + 4 * s + l4) ^ (l15 & 7);
        bf16x8 a0 = *(const bf16x8*)&As[((size_t)l15 * 96 + cc) * 8];
        bf16x8 a1 = *(const bf16x8*)&As[((size_t)(l15 + 16) * 96 + cc) * 8];
#pragma unroll
        for (int nt = 0; nt < 4; ++nt) {
          acc[0][nt] = __builtin_amdgcn_mfma_f32_16x16x32_bf16(a0, Bfr[s][nt], acc[0][nt], 0, 0, 0);
          acc[1][nt] = __builtin_amdgcn_mfma_f32_16x16x32_bf16(a1, Bfr[s][nt], acc[1][nt], 0, 0, 0);
        }
      }
      // partials -> Pk[kh][16t+4l4+r][64g+16nt+l15]
      float* Pw = Pk + 4224 * kh;
#pragma unroll
      for (int t = 0; t < 2; ++t)
#pragma unroll
        for (int nt = 0; nt < 4; ++nt)
#pragma unroll
          for (int r = 0; r < 4; ++r)
            Pw[(16 * t + 4 * l4 + r) * 132 + 64 * g + 16 * nt + l15] = acc[t][nt][r];
      __syncthreads();   // partials done
      // reduce K-halves + bias, store 16 cols per thread directly to Kx/Vx
      {
        u16 ob16[16];
#pragma unroll
        for (int u = 0; u < 4; ++u) {
          f32x4 v = *(const f32x4*)&Pk[rrow * 132 + rc + 4 * u];
          v += *(const f32x4*)&Pk[4224 + rrow * 132 + rc + 4 * u];
#pragma unroll
          for (int e = 0; e < 4; ++e) ob16[4 * u + e] = f2bf(v[e] + biasr[4 * u + e]);
        }
        u16* ob = obase + (size_t)i * NB * HID + (size_t)rrow * HID + oc0 + rc;
#pragma unroll
        for (int q = 0; q < 4; ++q) {
          u64 w8; __builtin_memcpy(&w8, &ob16[4 * q], 8);
          cst64(ob + 4 * q, w8);
        }
      }
      g_arrive(ctr, bid, z);   // stamp z=i+2 also serves as "Kx/Vx row i ready"
      g_wait(ctr, z, sep); ++z;
    }
  } else {
    // ------- attention: 4 waves, one batch each ------------------------------
    const int b = (bid - 60) * 4 + wid;
    u16* sb = (u16*)SH + wid * 2304;                     // [3][768]
    int* spng = (int*)(SH + 18432) + wid * 512;
    for (int j = lane; j < TLEN; j += 64) spng[j] = P.ping[(size_t)b * TLEN + j];
    {  // prologue: row_0 = x[0] (t=0 mask false)
      const size_t xoff = (size_t)b * HID + 12 * lane;
      u16* orow = P.rowbuf + (size_t)b * HID + 12 * lane;
#pragma unroll
      for (int q = 0; q < 3; ++q) {
        u16 e[4];
#pragma unroll
        for (int t2 = 0; t2 < 4; ++t2) e[t2] = ldbf(P.x, xoff + 4 * q + t2, f);
        u64 w8; __builtin_memcpy(&w8, e, 8);
        cst64(orow + 4 * q, w8);
      }
    }
    g_arrive(ctr, bid, z); g_wait(ctr, z, sep); ++z;   // prologue

    for (int i = 0; i < TLEN; ++i) {
      if (i < TLEN - 1) {
        const int t = i + 1;
        const int p = spng[t];
        u16* orow = P.rowbuf + (size_t)(t & 1) * NB * HID + (size_t)b * HID;
        if (p == 0) {  // mask false -> row = x[t]
          const size_t xoff = ((size_t)t * NB + b) * HID + 12 * lane;
#pragma unroll
          for (int q = 0; q < 3; ++q) {
            u16 e[4];
#pragma unroll
            for (int t2 = 0; t2 < 4; ++t2) e[t2] = ldbf(P.x, xoff + 4 * q + t2, f);
            u64 w8; __builtin_memcpy(&w8, e, 8);
            cst64(orow + 12 * lane + 4 * q, w8);
          }
        } else {
          const int idx = p - 1;
          // q / right-key / right-value: static rows, plain loads, issued early
          const u16* qp = P.Qx + ((size_t)t * NB + b) * HID;  // never rewritten
          const u16* kR = P.Kx + ((size_t)t * NB + b) * HID;  // untouched until interval t
          const u16* vR = P.Vx + ((size_t)t * NB + b) * HID;
          float qv[12], krv[12], vrv[12];
#pragma unroll
          for (int j = 0; j < 12; ++j) {
            qv[j]  = bf2f(qp[64 * j + lane]);
            krv[j] = bf2f(kR[64 * j + lane]);
            vrv[j] = bf2f(vR[64 * j + lane]);
          }
          if (idx == i) {  // produced this interval: wait for the 12 kv blocks
            const u32 tgt = (u32)(i + 2);
            for (;;) {
              u32 v = tgt;
              if (lane < 12)
                v = __hip_atomic_load(&ctr[48 + lane], __ATOMIC_RELAXED, __HIP_MEMORY_SCOPE_AGENT);
              if (__all(v >= tgt)) break;
              __builtin_amdgcn_s_sleep(2);
            }
            asm volatile("" ::: "memory");
          }
          const u16* kL = P.Kx + ((size_t)idx * NB + b) * HID;
          const u16* vL = P.Vx + ((size_t)idx * NB + b) * HID;
#pragma unroll
          for (int q = 0; q < 3; ++q) {
            *(u64*)&sb[12 * lane + 4 * q]       = cld64(kL + 12 * lane + 4 * q);
            *(u64*)&sb[768 + 12 * lane + 4 * q] = cld64(vL + 12 * lane + 4 * q);
          }
          wfence();
          float d0[12], d1[12];
#pragma unroll
          for (int j = 0; j < 12; ++j) {
            d0[j] = qv[j] * bf2f(sb[64 * j + lane]);
            d1[j] = qv[j] * krv[j];
          }
#pragma unroll
          for (int m = 32; m > 0; m >>= 1) {
#pragma unroll
            for (int j = 0; j < 12; ++j) {
              d0[j] += __shfl_xor(d0[j], m);
              d1[j] += __shfl_xor(d1[j], m);
            }
          }
#pragma unroll
          for (int j = 0; j < 12; ++j) {
            float pw0 = sigm((d0[j] - d1[j]) * 0.125f);  // softmax over 2 keys
            float ov = pw0 * bf2f(sb[768 + 64 * j + lane]) + (1.0f - pw0) * vrv[j];
            sb[1536 + 64 * j + lane] = f2bf(ov);
          }
          wfence();
#pragma unroll
          for (int q = 0; q < 3; ++q) {
            u64 w8; __builtin_memcpy(&w8, &sb[1536 + 12 * lane + 4 * q], 8);
            cst64(orow + 12 * lane + 4 * q, w8);
          }
        }
      }
      g_arrive(ctr, bid, z); g_wait(ctr, z, sep); ++z;
    }
  }
}

extern "C" void kernel_launch(void* const* d_in, const int* in_sizes, int n_in,
                              void* d_out, int out_size, void* d_ws, size_t ws_size,
                              hipStream_t stream) {
  const void* x   = d_in[0];
  const int* ping = (const int*)d_in[1];
  const void* h0  = d_in[2];
  const void* c0  = d_in[3];
  const void* wih = d_in[4];
  const void* whh = d_in[5];
  const void* bih = d_in[6];
  const void* bhh = d_in[7];
  const void* wq  = d_in[8];
  const void* bq  = d_in[9];
  const void* wk  = d_in[10];
  const void* bk  = d_in[11];
  const void* wv  = d_in[12];
  const void* bv  = d_in[13];
  (void)in_sizes; (void)n_in; (void)out_size; (void)ws_size;  // needs ~90 MB ws

  char* ws = (char*)d_ws;
  size_t off = 0;
  auto walloc = [&](size_t b) { char* p = ws + off; off += (b + 255) & ~(size_t)255; return p; };
  u32* ctr    = (u32*)walloc(2048);
  u32* flag   = ctr + 400;  // clear of slots 0..67
  u16* WqkvT  = (u16*)walloc((size_t)2304 * 768 * 2);
  u16* WihT   = (u16*)walloc((size_t)3072 * 768 * 2);
  u16* WhhT   = (u16*)walloc((size_t)3072 * 768 * 2);
  u16* Qx     = (u16*)walloc((size_t)TLEN * NB * HID * 2);
  u16* Kx     = (u16*)walloc((size_t)TLEN * NB * HID * 2);
  u16* Vx     = (u16*)walloc((size_t)TLEN * NB * HID * 2);
  u16* rowbuf = (u16*)walloc((size_t)2 * NB * HID * 2);
  u16* h0b    = (u16*)walloc((size_t)NB * HID * 2);
  float* c0f  = (float*)walloc((size_t)NB * HID * 4);
  u16* hsb    = (u16*)walloc((size_t)2 * NB * HID * 2);

  hipMemsetAsync(ctr, 0, 2048, stream);
  prologue<<<1, 256, 0, stream>>>(x, h0, c0, flag, h0b, c0f);
  transpose_any<<<dim3(12, 12), 256, 0, stream>>>(wq, WqkvT, 768, 768, flag);
  transpose_any<<<dim3(12, 12), 256, 0, stream>>>(wk, WqkvT + (size_t)768 * 768, 768, 768, flag);
  transpose_any<<<dim3(12, 12), 256, 0, stream>>>(wv, WqkvT + (size_t)1536 * 768, 768, 768, flag);
  transpose_any<<<dim3(48, 12), 256, 0, stream>>>(wih, WihT, 768, 3072, flag);
  transpose_any<<<dim3(48, 12), 256, 0, stream>>>(whh, WhhT, 768, 3072, flag);
  qkv_gemm<<<dim3(128, 18), 256, 0, stream>>>(x, WqkvT, bq, bk, bv, Qx, Kx, Vx, flag);

  ScanParams P;
  P.x = x; P.bih = bih; P.bhh = bhh; P.bk = bk; P.bv = bv;
  P.h0b = h0b; P.c0f = c0f;
  P.ping = ping;
  P.WihT = WihT; P.WhhT = WhhT; P.WqkvT = WqkvT;
  P.Qx = Qx; P.Kx = Kx; P.Vx = Vx;
  P.rowbuf = rowbuf; P.hsb = hsb;
  P.out = d_out;
  P.ctr = ctr; P.flag = flag;
  scan_kernel<<<dim3(NBLK), dim3(256), 0, stream>>>(P);
}

// Round 5
// 3085.349 us; speedup vs baseline: 3.3748x; 1.2572x over previous
//
#include <hip/hip_runtime.h>
#include <hip/hip_bf16.h>

#define TLEN 512
#define NB   32
#define HID  768
#define NBLK 68

typedef __attribute__((ext_vector_type(8))) short bf16x8;
typedef __attribute__((ext_vector_type(4))) float f32x4;
typedef unsigned short u16;
typedef unsigned int u32;
typedef unsigned long long u64;

__device__ __forceinline__ float bf2f(u16 u) {
  u32 t = ((u32)u) << 16; float f; __builtin_memcpy(&f, &t, 4); return f;
}
__device__ __forceinline__ u16 f2bf(float f) {
  u32 t; __builtin_memcpy(&t, &f, 4);
  u32 r = t + 0x7FFFu + ((t >> 16) & 1u);
  return (u16)(r >> 16);
}
// dual-dtype scalar loads: f!=0 -> input buffer is fp32, else packed bf16
__device__ __forceinline__ u16 ldbf(const void* p, size_t i, u32 f) {
  return f ? f2bf(((const float*)p)[i]) : ((const u16*)p)[i];
}
__device__ __forceinline__ float ldf(const void* p, size_t i, u32 f) {
  return f ? ((const float*)p)[i] : bf2f(((const u16*)p)[i]);
}
__device__ __forceinline__ float sigm(float x) { return 1.0f / (1.0f + __expf(-x)); }
__device__ __forceinline__ float tanh_(float x) { return 1.0f - 2.0f / (1.0f + __expf(2.0f * x)); }

// ---- agent-scope (cross-XCD coherent) accesses ----
__device__ __forceinline__ u64 cld64(const u16* p) {
  return __hip_atomic_load((const u64*)p, __ATOMIC_RELAXED, __HIP_MEMORY_SCOPE_AGENT);
}
__device__ __forceinline__ void cst64(u16* p, u64 v) {
  __hip_atomic_store((u64*)p, v, __ATOMIC_RELAXED, __HIP_MEMORY_SCOPE_AGENT);
}
__device__ __forceinline__ bf16x8 cld128(const u16* p) {
  union { u64 q[2]; bf16x8 v; } u;
  u.q[0] = cld64(p); u.q[1] = cld64(p + 4);
  return u.v;
}
// wave-internal LDS fence (lockstep wave64: write->fence->read is safe)
__device__ __forceinline__ void wfence() {
  asm volatile("s_waitcnt lgkmcnt(0)" ::: "memory");
}
// poll n contiguous stamp slots until all >= tgt (coalesced lane-load)
__device__ __forceinline__ void waitSlots(const u32* base, int n, u32 tgt) {
  const int lane = threadIdx.x & 63;
  for (;;) {
    u32 v = tgt;
    if (lane < n)
      v = __hip_atomic_load(&base[lane], __ATOMIC_RELAXED, __HIP_MEMORY_SCOPE_AGENT);
    if (__all(v >= tgt)) break;
    __builtin_amdgcn_s_sleep(1);
  }
  asm volatile("" ::: "memory");
}
__device__ __forceinline__ void stamp(u32* slot, u32 v) {
  __hip_atomic_store(slot, v, __ATOMIC_RELAXED, __HIP_MEMORY_SCOPE_AGENT);
}

// ---------------- prologue: dtype sniff + h0/c0 conversion -------------------
__global__ __launch_bounds__(256) void prologue(const void* __restrict__ x,
                                                const void* __restrict__ h0,
                                                const void* __restrict__ c0,
                                                u32* __restrict__ flag,
                                                u16* __restrict__ h0b,
                                                float* __restrict__ c0f) {
  __shared__ u32 sflag;
  if (threadIdx.x == 0) {
    const u32* w = (const u32*)x;
    int cnt = 0;
    for (int m = 0; m < 256; ++m) {
      u32 e = ((w[m] & 0xFFFFu) >> 7) & 0xFFu;
      cnt += (e >= 100u && e <= 140u) ? 1 : 0;
    }
    sflag = (cnt >= 128) ? 0u : 1u;  // 1 = fp32 inputs
    flag[0] = sflag;
  }
  __syncthreads();
  const u32 f = sflag;
  for (int i = threadIdx.x; i < NB * HID; i += 256) {
    h0b[i] = ldbf(h0, i, f);
    c0f[i] = ldf(c0, i, f);
  }
}

// ---------------- transpose (R x C row-major -> C x R, emits bf16) ----------
__global__ __launch_bounds__(256) void transpose_any(const void* __restrict__ in,
                                                     u16* __restrict__ out, int R, int C,
                                                     const u32* __restrict__ flag) {
  const u32 f = flag[0];
  __shared__ u16 tile[64][65];
  int c0 = blockIdx.x * 64, r0 = blockIdx.y * 64;
  int tx = threadIdx.x & 63, ty = threadIdx.x >> 6;
#pragma unroll
  for (int j = 0; j < 16; ++j) {
    int r = ty + 4 * j;
    tile[r][tx] = ldbf(in, (size_t)(r0 + r) * C + c0 + tx, f);
  }
  __syncthreads();
#pragma unroll
  for (int j = 0; j < 16; ++j) {
    int r = ty + 4 * j;
    out[(size_t)(c0 + r) * R + r0 + tx] = tile[tx][r];
  }
}

// ---------------- QKV precompute: [16384 x 768] @ [768 x 2304] --------------
__global__ __launch_bounds__(256) void qkv_gemm(const void* __restrict__ X, const u16* __restrict__ WT,
                                                const void* __restrict__ bq, const void* __restrict__ bk,
                                                const void* __restrict__ bv,
                                                u16* __restrict__ Qx, u16* __restrict__ Kx,
                                                u16* __restrict__ Vx, const u32* __restrict__ flag) {
  const u32 f = flag[0];
  __shared__ __align__(16) u16 As[128][40];
  __shared__ __align__(16) u16 Bs[128][40];
  const int m0 = blockIdx.x * 128;
  const int n0 = blockIdx.y * 128;
  const int tid = threadIdx.x;
  const int lane = tid & 63, w = tid >> 6;
  const int l15 = lane & 15, l4 = lane >> 4;
  f32x4 zero4 = {0.f, 0.f, 0.f, 0.f};
  f32x4 acc[2][8];
#pragma unroll
  for (int h = 0; h < 2; ++h)
#pragma unroll
    for (int nt = 0; nt < 8; ++nt) acc[h][nt] = zero4;
  const int srow = tid >> 1, skp = (tid & 1) * 16;
  for (int k0 = 0; k0 < 768; k0 += 32) {
    __syncthreads();
    if (f) {
      const float* Xf = (const float*)X + (size_t)(m0 + srow) * 768 + k0 + skp;
#pragma unroll
      for (int q = 0; q < 16; ++q) As[srow][skp + q] = f2bf(Xf[q]);
    } else {
      const u16* Xh = (const u16*)X + (size_t)(m0 + srow) * 768 + k0 + skp;
      *(bf16x8*)&As[srow][skp]     = *(const bf16x8*)(Xh);
      *(bf16x8*)&As[srow][skp + 8] = *(const bf16x8*)(Xh + 8);
    }
    *(bf16x8*)&Bs[srow][skp]     = *(const bf16x8*)(WT + (size_t)(n0 + srow) * 768 + k0 + skp);
    *(bf16x8*)&Bs[srow][skp + 8] = *(const bf16x8*)(WT + (size_t)(n0 + srow) * 768 + k0 + skp + 8);
    __syncthreads();
    const int kl = 8 * l4;
    bf16x8 a0 = *(const bf16x8*)&As[32 * w + l15][kl];
    bf16x8 a1 = *(const bf16x8*)&As[32 * w + 16 + l15][kl];
#pragma unroll
    for (int nt = 0; nt < 8; ++nt) {
      bf16x8 b = *(const bf16x8*)&Bs[16 * nt + l15][kl];
      acc[0][nt] = __builtin_amdgcn_mfma_f32_16x16x32_bf16(a0, b, acc[0][nt], 0, 0, 0);
      acc[1][nt] = __builtin_amdgcn_mfma_f32_16x16x32_bf16(a1, b, acc[1][nt], 0, 0, 0);
    }
  }
#pragma unroll
  for (int h = 0; h < 2; ++h)
#pragma unroll
    for (int nt = 0; nt < 8; ++nt)
#pragma unroll
      for (int r = 0; r < 4; ++r) {
        const int m = m0 + 32 * w + 16 * h + 4 * l4 + r;
        const int n = n0 + 16 * nt + l15;
        float bias; u16* dst;
        if (n < 768)       { bias = ldf(bq, n, f);        dst = Qx + (size_t)m * 768 + n; }
        else if (n < 1536) { bias = ldf(bk, n - 768, f);  dst = Kx + (size_t)m * 768 + (n - 768); }
        else               { bias = ldf(bv, n - 1536, f); dst = Vx + (size_t)m * 768 + (n - 1536); }
        *dst = f2bf(acc[h][nt][r] + bias);
      }
}

// ---------------- persistent sequential scan ---------------------------------
// 68 blocks x 256 threads. Point-to-point stamps instead of a global barrier:
//   attnStamp[32] @ctr[0..31]   : attn wave aw published rowbuf row_t -> t+1
//   gateStaged[48]@ctr[64..111] : gates block staged (row|h) of interval i -> i+1
//   kvStaged[12]  @ctr[112..123]: kv block staged row of interval i -> i+1
//   gateH[48]     @ctr[128..175]: gates block drained h_i -> i+1
//   kvStamp[12]   @ctr[192..203]: kv block drained Kx/Vx row i -> i+1
// Critical cycle is the h-chain only (gates: wait gateH -> stage h -> GEMM ->
// pointwise -> drain -> stamp gateH). Row staging overlaps the h wait; kv and
// attn run concurrently off the h-path (attn needs only the early "staged"
// stamps; kv needs only attnStamp).
struct ScanParams {
  const void *x, *bih, *bhh, *bk, *bv;
  const u16 *h0b;
  const float *c0f;
  const int* ping;
  const u16 *WihT, *WhhT, *WqkvT;
  const u16 *Qx;
  u16 *Kx, *Vx;
  u16 *rowbuf, *hsb;
  void* out;
  u32 *ctr;
  const u32* flag;
};

__global__ __launch_bounds__(256, 1) void scan_kernel(ScanParams P) {
  // LDS layout (union across roles):
  //  gates: As 0..98304 | Pp 98304..133120 ([4][32][68] f32) | htile 133120..134144
  //         | biasT 134144..134400
  //  kv:    As 0..49152 | Pk 49152..82944 ([2][32][132] f32)
  //  attn:  sbuf 0..18432 | sping 18432..26624
  __shared__ __align__(16) unsigned char SH[134416];
  const int bid = blockIdx.x;
  const int tid = threadIdx.x;
  const int wid = tid >> 6;
  const int lane = tid & 63;
  const int l15 = lane & 15, l4 = lane >> 4;
  const u32 f = P.flag[0];
  u32* ctr = P.ctr;

  if (bid < 48) {
    u16* As = (u16*)SH;                       // [32 rows][192 chunks][8], XOR-swizzled
    float* Pp = (float*)(SH + 98304);         // [4][32][68] partial gate sums
    u16* htile = (u16*)(SH + 133120);         // [32][16]
    float* biasT = (float*)(SH + 134144);     // [64] = bias[4m+q]
    const int jb = 16 * bid;                  // block's 16 hidden cols
    const int w = wid;
    const int cq = l15 & 3, cm4 = l15 >> 2;   // col n=16nt+l15 <-> (q=cq, m=4nt+cm4)
    // ---- B fragments: wave w covers K-range [384*(w&1), +384) of Wih (w<2) or Whh ----
    bf16x8 Bfr[12][4];
    {
      const u16* WT = (w < 2) ? P.WihT : P.WhhT;
      const int kbase = 384 * (w & 1);
#pragma unroll
      for (int s = 0; s < 12; ++s)
#pragma unroll
        for (int nt = 0; nt < 4; ++nt) {
          const int colW = 768 * cq + jb + 4 * nt + cm4;
          Bfr[s][nt] = *(const bf16x8*)(WT + (size_t)colW * HID + kbase + 32 * s + 8 * l4);
        }
    }
    if (w == 0) {  // bias table: biasT[4m+q]
      const int m_ = lane >> 2, q_ = lane & 3;
      biasT[lane] = ldf(P.bih, 768 * q_ + jb + m_, f) + ldf(P.bhh, 768 * q_ + jb + m_, f);
    }
    const int cb = 8 * w + (lane >> 3), cm = lane & 7;  // this lane's cells (cb,cm),(cb,cm+8)
    float cst0 = P.c0f[(size_t)cb * HID + jb + cm];
    float cst1 = P.c0f[(size_t)cb * HID + jb + cm + 8];

    for (int i = 0; i < TLEN; ++i) {
      const u16* rowp = P.rowbuf + (size_t)(i & 1) * NB * HID;
      const u16* hp = (i == 0) ? P.h0b : (P.hsb + (size_t)((i - 1) & 1) * NB * HID);
      waitSlots(ctr, 32, (u32)(i + 1));       // row_i published by all attn waves
      // ---- stage ROW half (logical chunks c<96) ----
      {
        bf16x8 stg[12];
#pragma unroll
        for (int j = 0; j < 12; ++j) {
          const int g2 = tid + 256 * j;
          const int r = g2 / 96, c = g2 - r * 96;
          stg[j] = cld128(rowp + (size_t)r * HID + c * 8);
        }
#pragma unroll
        for (int j = 0; j < 12; ++j) {
          const int g2 = tid + 256 * j;
          const int r = g2 / 96, c = g2 - r * 96;
          *(bf16x8*)&As[((size_t)r * 192 + (c ^ (r & 7))) * 8] = stg[j];
        }
      }
      if (i) waitSlots(ctr + 128, 48, (u32)i);  // h_{i-1} drained by all gates blocks
      // ---- stage H half (logical chunks 96..191) ----
      {
        bf16x8 stg[12];
#pragma unroll
        for (int j = 0; j < 12; ++j) {
          const int g2 = tid + 256 * j;
          const int r = g2 / 96, c = g2 - r * 96;
          stg[j] = cld128(hp + (size_t)r * HID + c * 8);
        }
#pragma unroll
        for (int j = 0; j < 12; ++j) {
          const int g2 = tid + 256 * j;
          const int r = g2 / 96, c = g2 - r * 96;
          *(bf16x8*)&As[((size_t)r * 192 + ((c + 96) ^ (r & 7))) * 8] = stg[j];
        }
      }
      __syncthreads();   // sync1: As staged (=> all global row loads complete)
      if (tid == 0) stamp(&ctr[64 + bid], (u32)(i + 1));   // rowbuf_i consumed
      f32x4 zero4 = {0.f, 0.f, 0.f, 0.f};
      f32x4 acc[2][4];
#pragma unroll
      for (int h = 0; h < 2; ++h)
#pragma unroll
        for (int nt = 0; nt < 4; ++nt) acc[h][nt] = zero4;
      const int cbase = 48 * w;
#pragma unroll
      for (int s = 0; s < 12; ++s) {
        const int cc = (cbase + 4 * s + l4) ^ (l15 & 7);
        bf16x8 a0 = *(const bf16x8*)&As[((size_t)l15 * 192 + cc) * 8];
        bf16x8 a1 = *(const bf16x8*)&As[((size_t)(l15 + 16) * 192 + cc) * 8];
#pragma unroll
        for (int nt = 0; nt < 4; ++nt) {
          acc[0][nt] = __builtin_amdgcn_mfma_f32_16x16x32_bf16(a0, Bfr[s][nt], acc[0][nt], 0, 0, 0);
          acc[1][nt] = __builtin_amdgcn_mfma_f32_16x16x32_bf16(a1, Bfr[s][nt], acc[1][nt], 0, 0, 0);
        }
      }
      // partials -> LDS [w][row][16nt + 4cm4 + cq]
      float* Pw = Pp + 2176 * w;
#pragma unroll
      for (int h = 0; h < 2; ++h)
#pragma unroll
        for (int nt = 0; nt < 4; ++nt)
#pragma unroll
          for (int r = 0; r < 4; ++r)
            Pw[(16 * h + 4 * l4 + r) * 68 + 16 * nt + 4 * cm4 + cq] = acc[h][nt][r];
      __syncthreads();   // sync2
      // reduce 4 partials + bias; pointwise for cells (cb,cm),(cb,cm+8)
      f32x4 g0 = *(const f32x4*)&biasT[4 * cm];
      f32x4 g1 = *(const f32x4*)&biasT[4 * (cm + 8)];
#pragma unroll
      for (int w2 = 0; w2 < 4; ++w2) {
        g0 += *(const f32x4*)&Pp[2176 * w2 + 68 * cb + 4 * cm];
        g1 += *(const f32x4*)&Pp[2176 * w2 + 68 * cb + 4 * (cm + 8)];
      }
      cst0 = sigm(g0[1]) * cst0 + sigm(g0[0]) * tanh_(g0[2]);
      cst1 = sigm(g1[1]) * cst1 + sigm(g1[0]) * tanh_(g1[2]);
      float h0v = sigm(g0[3]) * tanh_(cst0);
      float h1v = sigm(g1[3]) * tanh_(cst1);
      htile[cb * 16 + cm] = f2bf(h0v);
      htile[cb * 16 + cm + 8] = f2bf(h1v);
      wfence();          // same-wave htile rows complete
      if (lane < 32) {   // wave w flushes its own 8 batch-rows (16 cols = 4x8B)
        const int b = 8 * w + (lane >> 2), part = lane & 3;
        u64 hv; __builtin_memcpy(&hv, &htile[b * 16 + 4 * part], 8);
        cst64(P.hsb + (size_t)(i & 1) * NB * HID + (size_t)b * HID + jb + 4 * part, hv);
      }
      __builtin_amdgcn_s_waitcnt(0);   // drain h stores
      __syncthreads();                 // sync3: all waves drained; As reusable
      if (tid == 0) stamp(&ctr[128 + bid], (u32)(i + 1));  // h_i ready
      // out stores off the critical path (drained by next step's waitcnt)
      const size_t o1 = (size_t)i * NB * HID + (size_t)cb * HID + jb + cm;
      if (f) { float* O = (float*)P.out; O[o1] = h0v; O[o1 + 8] = h1v; }
      else   { u16*   O = (u16*)P.out;   O[o1] = f2bf(h0v); O[o1 + 8] = f2bf(h1v); }
      if (i == TLEN - 1) {
        const size_t oh = (size_t)TLEN * NB * HID + (size_t)cb * HID + jb + cm;
        const size_t oc = (size_t)(TLEN + 1) * NB * HID + (size_t)cb * HID + jb + cm;
        if (f) { float* O = (float*)P.out; O[oh] = h0v; O[oh + 8] = h1v; O[oc] = cst0; O[oc + 8] = cst1; }
        else   { u16*   O = (u16*)P.out;   O[oh] = f2bf(h0v); O[oh + 8] = f2bf(h1v);
                 O[oc] = f2bf(cst0); O[oc + 8] = f2bf(cst1); }
      }
    }
  } else if (bid < 60) {
    // ------- k/v projection: K-split-2, wave = (64-col group g) x (K-half kh) --
    u16* As = (u16*)SH;                                  // [32][96 chunks][8]
    float* Pk = (float*)(SH + 49152);                    // [2][32][132]
    const int kb = bid - 48;
    const int col0 = 128 * kb;                           // within [K|V] concat (1536)
    const bool isV = kb >= 6;
    const int oc0 = col0 - (isV ? 768 : 0);
    u16* obase = isV ? P.Vx : P.Kx;
    const void* bias_src = isV ? P.bv : P.bk;
    const int g = wid & 1, kh = wid >> 1;
    const u16* Wt = P.WqkvT + (size_t)(768 + col0 + 64 * g) * HID;
    const int kbase = 384 * kh;
    bf16x8 Bfr[12][4];
#pragma unroll
    for (int s = 0; s < 12; ++s)
#pragma unroll
      for (int nt = 0; nt < 4; ++nt)
        Bfr[s][nt] = *(const bf16x8*)(Wt + (size_t)(16 * nt + l15) * HID + kbase + 32 * s + 8 * l4);
    // reduce-phase personal constants: thread -> (rrow, 16-col chunk rc)
    const int rrow = tid >> 3, rc = (tid & 7) * 16;
    float biasr[16];
#pragma unroll
    for (int e = 0; e < 16; ++e) biasr[e] = ldf(bias_src, oc0 + rc + e, f);

    for (int i = 0; i < TLEN; ++i) {
      const u16* rowp = P.rowbuf + (size_t)(i & 1) * NB * HID;
      waitSlots(ctr, 32, (u32)(i + 1));       // row_i published
      // ---- cooperative staging of row (32x768 bf16), 2 rounds ----
#pragma unroll
      for (int half = 0; half < 2; ++half) {
        bf16x8 stg[6];
#pragma unroll
        for (int j = 0; j < 6; ++j) {
          const int g2 = tid + 256 * (6 * half + j);
          const int r = g2 / 96, c = g2 - r * 96;
          stg[j] = cld128(rowp + (size_t)r * HID + c * 8);
        }
#pragma unroll
        for (int j = 0; j < 6; ++j) {
          const int g2 = tid + 256 * (6 * half + j);
          const int r = g2 / 96, c = g2 - r * 96;
          *(bf16x8*)&As[((size_t)r * 96 + (c ^ (r & 7))) * 8] = stg[j];
        }
      }
      __syncthreads();   // As staged
      if (tid == 0) stamp(&ctr[112 + kb], (u32)(i + 1));   // rowbuf_i consumed
      f32x4 zero4 = {0.f, 0.f, 0.f, 0.f};
      f32x4 acc[2][4];
#pragma unroll
      for (int t = 0; t < 2; ++t)
#pragma unroll
        for (int nt = 0; nt < 4; ++nt) acc[t][nt] = zero4;
      const int cbase = 48 * kh;
#pragma unroll
      for (int s = 0; s < 12; ++s) {
        const int cc = (cbase + 4 * s + l4) ^ (l15 & 7);
        bf16x8 a0 = *(const bf16x8*)&As[((size_t)l15 * 96 + cc) * 8];
        bf16x8 a1 = *(const bf16x8*)&As[((size_t)(l15 + 16) * 96 + cc) * 8];
#pragma unroll
        for (int nt = 0; nt < 4; ++nt) {
          acc[0][nt] = __builtin_amdgcn_mfma_f32_16x16x32_bf16(a0, Bfr[s][nt], acc[0][nt], 0, 0, 0);
          acc[1][nt] = __builtin_amdgcn_mfma_f32_16x16x32_bf16(a1, Bfr[s][nt], acc[1][nt], 0, 0, 0);
        }
      }
      // partials -> Pk[kh][16t+4l4+r][64g+16nt+l15]
      float* Pw = Pk + 4224 * kh;
#pragma unroll
      for (int t = 0; t < 2; ++t)
#pragma unroll
        for (int nt = 0; nt < 4; ++nt)
#pragma unroll
          for (int r = 0; r < 4; ++r)
            Pw[(16 * t + 4 * l4 + r) * 132 + 64 * g + 16 * nt + l15] = acc[t][nt][r];
      __syncthreads();   // partials done
      // reduce K-halves + bias, store 16 cols per thread directly to Kx/Vx
      {
        u16 ob16[16];
#pragma unroll
        for (int u = 0; u < 4; ++u) {
          f32x4 v = *(const f32x4*)&Pk[rrow * 132 + rc + 4 * u];
          v += *(const f32x4*)&Pk[4224 + rrow * 132 + rc + 4 * u];
#pragma unroll
          for (int e = 0; e < 4; ++e) ob16[4 * u + e] = f2bf(v[e] + biasr[4 * u + e]);
        }
        u16* ob = obase + (size_t)i * NB * HID + (size_t)rrow * HID + oc0 + rc;
#pragma unroll
        for (int q = 0; q < 4; ++q) {
          u64 w8; __builtin_memcpy(&w8, &ob16[4 * q], 8);
          cst64(ob + 4 * q, w8);
        }
      }
      __builtin_amdgcn_s_waitcnt(0);   // drain Kx/Vx stores
      __syncthreads();                 // all waves drained; As reusable
      if (tid == 0) stamp(&ctr[192 + kb], (u32)(i + 1));   // Kx/Vx row i ready
    }
  } else {
    // ------- attention: 4 independent waves, one batch each -------------------
    const int aw = (bid - 60) * 4 + wid;                 // 0..31
    const int b = aw;
    u16* sb = (u16*)SH + wid * 2304;                     // [3][768]
    int* spng = (int*)(SH + 18432) + wid * 512;
    for (int j = lane; j < TLEN; j += 64) spng[j] = P.ping[(size_t)b * TLEN + j];
    {  // prologue: row_0 = x[0] (t=0 mask false)
      const size_t xoff = (size_t)b * HID + 12 * lane;
      u16* orow = P.rowbuf + (size_t)b * HID + 12 * lane;
#pragma unroll
      for (int q = 0; q < 3; ++q) {
        u16 e[4];
#pragma unroll
        for (int t2 = 0; t2 < 4; ++t2) e[t2] = ldbf(P.x, xoff + 4 * q + t2, f);
        u64 w8; __builtin_memcpy(&w8, e, 8);
        cst64(orow + 4 * q, w8);
      }
    }
    __builtin_amdgcn_s_waitcnt(0);
    if (lane == 0) stamp(&ctr[aw], 1u);                  // row_0 published

    for (int i = 0; i < TLEN - 1; ++i) {
      const int t = i + 1;
      // WAR: rowbuf parity (t&1) was last staged by gates/kv at interval i-1
      if (i) waitSlots(ctr + 64, 60, (u32)i);
      const int p = spng[t];
      u16* orow = P.rowbuf + (size_t)(t & 1) * NB * HID + (size_t)b * HID;
      if (p == 0) {  // mask false -> row = x[t]
        const size_t xoff = ((size_t)t * NB + b) * HID + 12 * lane;
#pragma unroll
        for (int q = 0; q < 3; ++q) {
          u16 e[4];
#pragma unroll
          for (int t2 = 0; t2 < 4; ++t2) e[t2] = ldbf(P.x, xoff + 4 * q + t2, f);
          u64 w8; __builtin_memcpy(&w8, e, 8);
          cst64(orow + 12 * lane + 4 * q, w8);
        }
      } else {
        const int idx = p - 1;
        // q / right-key / right-value: static rows, plain loads, issued early
        const u16* qp = P.Qx + ((size_t)t * NB + b) * HID;  // never rewritten
        const u16* kR = P.Kx + ((size_t)t * NB + b) * HID;  // untouched until interval t
        const u16* vR = P.Vx + ((size_t)t * NB + b) * HID;
        float qv[12], krv[12], vrv[12];
#pragma unroll
        for (int j = 0; j < 12; ++j) {
          qv[j]  = bf2f(qp[64 * j + lane]);
          krv[j] = bf2f(kR[64 * j + lane]);
          vrv[j] = bf2f(vR[64 * j + lane]);
        }
        // rows <= i-2 are guaranteed drained (kvStaged >= i implies interval
        // i-2 complete); rows i-1 and i need an explicit kvStamp wait.
        if (idx == i || idx + 1 == i) waitSlots(ctr + 192, 12, (u32)(idx + 1));
        const u16* kL = P.Kx + ((size_t)idx * NB + b) * HID;
        const u16* vL = P.Vx + ((size_t)idx * NB + b) * HID;
#pragma unroll
        for (int q = 0; q < 3; ++q) {
          *(u64*)&sb[12 * lane + 4 * q]       = cld64(kL + 12 * lane + 4 * q);
          *(u64*)&sb[768 + 12 * lane + 4 * q] = cld64(vL + 12 * lane + 4 * q);
        }
        wfence();
        float d0[12], d1[12];
#pragma unroll
        for (int j = 0; j < 12; ++j) {
          d0[j] = qv[j] * bf2f(sb[64 * j + lane]);
          d1[j] = qv[j] * krv[j];
        }
#pragma unroll
        for (int m = 32; m > 0; m >>= 1) {
#pragma unroll
          for (int j = 0; j < 12; ++j) {
            d0[j] += __shfl_xor(d0[j], m);
            d1[j] += __shfl_xor(d1[j], m);
          }
        }
#pragma unroll
        for (int j = 0; j < 12; ++j) {
          float pw0 = sigm((d0[j] - d1[j]) * 0.125f);  // softmax over 2 keys
          float ov = pw0 * bf2f(sb[768 + 64 * j + lane]) + (1.0f - pw0) * vrv[j];
          sb[1536 + 64 * j + lane] = f2bf(ov);
        }
        wfence();
#pragma unroll
        for (int q = 0; q < 3; ++q) {
          u64 w8; __builtin_memcpy(&w8, &sb[1536 + 12 * lane + 4 * q], 8);
          cst64(orow + 12 * lane + 4 * q, w8);
        }
      }
      __builtin_amdgcn_s_waitcnt(0);   // drain row stores
      if (lane == 0) stamp(&ctr[aw], (u32)(i + 2));      // row_{i+1} published
    }
  }
}

extern "C" void kernel_launch(void* const* d_in, const int* in_sizes, int n_in,
                              void* d_out, int out_size, void* d_ws, size_t ws_size,
                              hipStream_t stream) {
  const void* x   = d_in[0];
  const int* ping = (const int*)d_in[1];
  const void* h0  = d_in[2];
  const void* c0  = d_in[3];
  const void* wih = d_in[4];
  const void* whh = d_in[5];
  const void* bih = d_in[6];
  const void* bhh = d_in[7];
  const void* wq  = d_in[8];
  const void* bq  = d_in[9];
  const void* wk  = d_in[10];
  const void* bk  = d_in[11];
  const void* wv  = d_in[12];
  const void* bv  = d_in[13];
  (void)in_sizes; (void)n_in; (void)out_size; (void)ws_size;  // needs ~90 MB ws

  char* ws = (char*)d_ws;
  size_t off = 0;
  auto walloc = [&](size_t b) { char* p = ws + off; off += (b + 255) & ~(size_t)255; return p; };
  u32* ctr    = (u32*)walloc(2048);
  u32* flag   = ctr + 400;  // clear of stamp slots 0..203
  u16* WqkvT  = (u16*)walloc((size_t)2304 * 768 * 2);
  u16* WihT   = (u16*)walloc((size_t)3072 * 768 * 2);
  u16* WhhT   = (u16*)walloc((size_t)3072 * 768 * 2);
  u16* Qx     = (u16*)walloc((size_t)TLEN * NB * HID * 2);
  u16* Kx     = (u16*)walloc((size_t)TLEN * NB * HID * 2);
  u16* Vx     = (u16*)walloc((size_t)TLEN * NB * HID * 2);
  u16* rowbuf = (u16*)walloc((size_t)2 * NB * HID * 2);
  u16* h0b    = (u16*)walloc((size_t)NB * HID * 2);
  float* c0f  = (float*)walloc((size_t)NB * HID * 4);
  u16* hsb    = (u16*)walloc((size_t)2 * NB * HID * 2);

  hipMemsetAsync(ctr, 0, 2048, stream);
  prologue<<<1, 256, 0, stream>>>(x, h0, c0, flag, h0b, c0f);
  transpose_any<<<dim3(12, 12), 256, 0, stream>>>(wq, WqkvT, 768, 768, flag);
  transpose_any<<<dim3(12, 12), 256, 0, stream>>>(wk, WqkvT + (size_t)768 * 768, 768, 768, flag);
  transpose_any<<<dim3(12, 12), 256, 0, stream>>>(wv, WqkvT + (size_t)1536 * 768, 768, 768, flag);
  transpose_any<<<dim3(48, 12), 256, 0, stream>>>(wih, WihT, 768, 3072, flag);
  transpose_any<<<dim3(48, 12), 256, 0, stream>>>(whh, WhhT, 768, 3072, flag);
  qkv_gemm<<<dim3(128, 18), 256, 0, stream>>>(x, WqkvT, bq, bk, bv, Qx, Kx, Vx, flag);

  ScanParams P;
  P.x = x; P.bih = bih; P.bhh = bhh; P.bk = bk; P.bv = bv;
  P.h0b = h0b; P.c0f = c0f;
  P.ping = ping;
  P.WihT = WihT; P.WhhT = WhhT; P.WqkvT = WqkvT;
  P.Qx = Qx; P.Kx = Kx; P.Vx = Vx;
  P.rowbuf = rowbuf; P.hsb = hsb;
  P.out = d_out;
  P.ctr = ctr; P.flag = flag;
  scan_kernel<<<dim3(NBLK), dim3(256), 0, stream>>>(P);
}